// Round 2
// baseline (983.774 us; speedup 1.0000x reference)
//
#include <hip/hip_runtime.h>
#include <math.h>

#define D_MODEL 1024
#define T_SEQ   1024
#define BATCH   4
#define NHEAD   16
#define HDIM    64

// keep counts: trunc(linspace(0.35,0.15,16)*64), min 1
__constant__ int KEEPC[16] = {22,21,20,19,18,18,17,16,15,14,13,13,12,11,10,9};

// ---------------------------------------------------------------------------
// Q projection with float64 accumulation: Y = x @ sign(W).T + bias.
// Rank order of |q| feeds a top-k decision; f32 accumulation noise (~2e-3)
// flips ~150 rows vs the f64 numpy gold (gap ~0.6). f64 accumulation of f32
// 4-term mini-dots has error ~1.6e-5 << gap -> decisions match gold.
// 64x64 tile, BK=16, 256 threads, 4x4 f64 accumulators.
// ---------------------------------------------------------------------------
__global__ __launch_bounds__(256, 2) void gemm_sign_f64(
    const float* __restrict__ A, const float* __restrict__ W,
    const float* __restrict__ Bi, float* __restrict__ Y)
{
    const int K = D_MODEL, N = D_MODEL;
    __shared__ float As[16][68];   // [k][m], row = 272B (16B multiple)
    __shared__ float Ws[16][68];   // [k][n], sign-applied

    int tid  = threadIdx.x;
    int bm   = blockIdx.y * 64;
    int bn   = blockIdx.x * 64;
    int lrow = tid >> 2;           // 0..63
    int lk   = (tid & 3) * 4;      // 0,4,8,12
    int ty   = tid >> 4;           // 0..15
    int tx   = tid & 15;           // 0..15

    double acc[4][4];
    #pragma unroll
    for (int i = 0; i < 4; i++)
        #pragma unroll
        for (int j = 0; j < 4; j++) acc[i][j] = 0.0;

    const float* aptr = A + (size_t)(bm + lrow) * K + lk;
    const float* wptr = W + (size_t)(bn + lrow) * K + lk;

    for (int k0 = 0; k0 < K; k0 += 16) {
        float4 a4 = *(const float4*)aptr;
        float4 w4 = *(const float4*)wptr;
        aptr += 16; wptr += 16;
        w4.x = (float)((w4.x > 0.f) - (w4.x < 0.f));
        w4.y = (float)((w4.y > 0.f) - (w4.y < 0.f));
        w4.z = (float)((w4.z > 0.f) - (w4.z < 0.f));
        w4.w = (float)((w4.w > 0.f) - (w4.w < 0.f));

        __syncthreads();
        As[lk + 0][lrow] = a4.x; As[lk + 1][lrow] = a4.y;
        As[lk + 2][lrow] = a4.z; As[lk + 3][lrow] = a4.w;
        Ws[lk + 0][lrow] = w4.x; Ws[lk + 1][lrow] = w4.y;
        Ws[lk + 2][lrow] = w4.z; Ws[lk + 3][lrow] = w4.w;
        __syncthreads();

        #pragma unroll
        for (int kk = 0; kk < 16; kk += 4) {
            float p[4][4];
            #pragma unroll
            for (int i = 0; i < 4; i++)
                #pragma unroll
                for (int j = 0; j < 4; j++) p[i][j] = 0.f;
            #pragma unroll
            for (int t = 0; t < 4; t++) {
                alignas(16) float av[4], wv[4];
                *(float4*)av = *(const float4*)&As[kk + t][ty * 4];
                *(float4*)wv = *(const float4*)&Ws[kk + t][tx * 4];
                #pragma unroll
                for (int i = 0; i < 4; i++)
                    #pragma unroll
                    for (int j = 0; j < 4; j++)
                        p[i][j] = fmaf(av[i], wv[j], p[i][j]);
            }
            #pragma unroll
            for (int i = 0; i < 4; i++)
                #pragma unroll
                for (int j = 0; j < 4; j++)
                    acc[i][j] += (double)p[i][j];
        }
    }

    #pragma unroll
    for (int i = 0; i < 4; i++) {
        float* yp = Y + (size_t)(bm + ty * 4 + i) * N + bn + tx * 4;
        const float* bp = Bi + bn + tx * 4;
        float4 o;
        o.x = (float)acc[i][0] + bp[0];
        o.y = (float)acc[i][1] + bp[1];
        o.z = (float)acc[i][2] + bp[2];
        o.w = (float)acc[i][3] + bp[3];
        *(float4*)yp = o;
    }
}

// ---------------------------------------------------------------------------
// GEMM: Y = A @ W^T + bias. A:(4096,1024) row-major, W:(1024,1024) row-major.
// 128x128 tile, BK=16, 256 threads, 8x8 accumulators per thread.
// z selects (W,bias,Y). amask: per (batch, head) 0/1 multiplier on A columns.
// ---------------------------------------------------------------------------
__global__ __launch_bounds__(256, 2) void gemm_bt(
    const float* __restrict__ A,
    const float* __restrict__ W0, const float* __restrict__ W1,
    const float* __restrict__ B0, const float* __restrict__ B1,
    float* __restrict__ Y0, float* __restrict__ Y1,
    const float* __restrict__ amask)
{
    const int K = D_MODEL, N = D_MODEL;
    int z = blockIdx.z;
    const float* W  = (z == 0) ? W0 : W1;
    const float* Bi = (z == 0) ? B0 : B1;
    float*       Y  = (z == 0) ? Y0 : Y1;

    __shared__ float As[16][132];   // [k][m]
    __shared__ float Ws[16][132];   // [k][n]

    int tid  = threadIdx.x;
    int bm   = blockIdx.y * 128;
    int bn   = blockIdx.x * 128;
    int lrow = tid >> 1;            // 0..127
    int lk   = (tid & 1) * 8;       // 0 or 8
    int ty   = tid >> 4;            // 0..15
    int tx   = tid & 15;            // 0..15
    int bidx = bm >> 10;            // batch index

    float acc[8][8];
    #pragma unroll
    for (int i = 0; i < 8; i++)
        #pragma unroll
        for (int j = 0; j < 8; j++) acc[i][j] = 0.f;

    const float* aptr = A + (size_t)(bm + lrow) * K + lk;
    const float* wptr = W + (size_t)(bn + lrow) * K + lk;

    for (int k0 = 0; k0 < K; k0 += 16) {
        float4 a0 = *(const float4*)(aptr);
        float4 a1 = *(const float4*)(aptr + 4);
        float4 w0 = *(const float4*)(wptr);
        float4 w1 = *(const float4*)(wptr + 4);
        aptr += 16; wptr += 16;

        if (amask) {
            float mv = amask[bidx * NHEAD + ((k0 + lk) >> 6)];
            a0.x *= mv; a0.y *= mv; a0.z *= mv; a0.w *= mv;
            a1.x *= mv; a1.y *= mv; a1.z *= mv; a1.w *= mv;
        }

        __syncthreads();
        As[lk + 0][lrow] = a0.x; As[lk + 1][lrow] = a0.y;
        As[lk + 2][lrow] = a0.z; As[lk + 3][lrow] = a0.w;
        As[lk + 4][lrow] = a1.x; As[lk + 5][lrow] = a1.y;
        As[lk + 6][lrow] = a1.z; As[lk + 7][lrow] = a1.w;
        Ws[lk + 0][lrow] = w0.x; Ws[lk + 1][lrow] = w0.y;
        Ws[lk + 2][lrow] = w0.z; Ws[lk + 3][lrow] = w0.w;
        Ws[lk + 4][lrow] = w1.x; Ws[lk + 5][lrow] = w1.y;
        Ws[lk + 6][lrow] = w1.z; Ws[lk + 7][lrow] = w1.w;
        __syncthreads();

        #pragma unroll
        for (int kk = 0; kk < 16; kk++) {
            alignas(16) float a8[8], b8[8];
            *(float4*)&a8[0] = *(const float4*)&As[kk][ty * 8];
            *(float4*)&a8[4] = *(const float4*)&As[kk][ty * 8 + 4];
            *(float4*)&b8[0] = *(const float4*)&Ws[kk][tx * 8];
            *(float4*)&b8[4] = *(const float4*)&Ws[kk][tx * 8 + 4];
            #pragma unroll
            for (int i = 0; i < 8; i++)
                #pragma unroll
                for (int j = 0; j < 8; j++)
                    acc[i][j] = fmaf(a8[i], b8[j], acc[i][j]);
        }
    }

    #pragma unroll
    for (int i = 0; i < 8; i++) {
        size_t row = (size_t)(bm + ty * 8 + i);
        float* yp = Y + row * N + bn + tx * 8;
        const float* bp = Bi + bn + tx * 8;
        float4 o0, o1;
        o0.x = acc[i][0] + bp[0]; o0.y = acc[i][1] + bp[1];
        o0.z = acc[i][2] + bp[2]; o0.w = acc[i][3] + bp[3];
        o1.x = acc[i][4] + bp[4]; o1.y = acc[i][5] + bp[5];
        o1.z = acc[i][6] + bp[6]; o1.w = acc[i][7] + bp[7];
        *(float4*)yp       = o0;
        *(float4*)(yp + 4) = o1;
    }
}

// ---------------------------------------------------------------------------
// RMS-normalize rows of 64 (per b,t,head). y==0: q (norm + top-k), y==1: k.
// ---------------------------------------------------------------------------
__global__ void normqk(float* __restrict__ Q, float* __restrict__ Kb)
{
    int tid  = threadIdx.x;
    int wid  = tid >> 6;
    int lane = tid & 63;
    long rid = (long)blockIdx.x * 4 + wid;       // 0..65535
    int isK  = blockIdx.y;
    int h    = (int)(rid & 15);
    long bt  = rid >> 4;

    float* p = (isK ? Kb : Q) + bt * D_MODEL + h * HDIM;
    float x = p[lane];
    float ss = x * x;
    #pragma unroll
    for (int off = 32; off > 0; off >>= 1) ss += __shfl_xor(ss, off);
    float rms = sqrtf(ss * (1.0f / 64.0f));
    float xn = x / (rms + 1e-6f);

    if (!isK) {
        float a = fabsf(xn);
        int cnt = 0;
        for (int j = 0; j < 64; j++) {
            float o = __shfl(a, j);
            cnt += (o > a) ? 1 : 0;
        }
        if (cnt >= KEEPC[h]) xn = 0.f;   // rank < keep  <=>  |x| >= thresh
    }
    p[lane] = xn;
}

// ---------------------------------------------------------------------------
// Flash-style causal attention per (b,h,q-tile of 64). Also accumulates
// sum(attn^2) into He[b*16+h] (f64 atomics).
// ---------------------------------------------------------------------------
#define APAD 68
__global__ __launch_bounds__(256, 2) void attn_kernel(
    const float* __restrict__ Qg, const float* __restrict__ Kg,
    const float* __restrict__ Vg, float* __restrict__ Ctx,
    double* __restrict__ He)
{
    __shared__ float Qs[64][APAD];   // [d][t]
    __shared__ float Ks[64][APAD];   // [d][c]
    __shared__ float Vs[64][APAD];   // [c][d]
    __shared__ float Ps[64][APAD];   // [c][r]
    __shared__ float alphaS[64], linvS[64];

    int tid = threadIdx.x;
    int qt = blockIdx.x, h = blockIdx.y, b = blockIdx.z;
    const int C = D_MODEL;
    size_t headoff = (size_t)b * T_SEQ * C + h * HDIM;

    {   // load Q tile transposed
        int t  = tid >> 2;
        int dq = (tid & 3) << 4;
        const float* qp = Qg + headoff + (size_t)(qt * 64 + t) * C + dq;
        #pragma unroll
        for (int j = 0; j < 4; j++) {
            float4 v4 = *(const float4*)(qp + 4 * j);
            Qs[dq + 4 * j + 0][t] = v4.x;
            Qs[dq + 4 * j + 1][t] = v4.y;
            Qs[dq + 4 * j + 2][t] = v4.z;
            Qs[dq + 4 * j + 3][t] = v4.w;
        }
    }

    float m = -1e30f, l = 0.f, s2 = 0.f;     // live in wave 0 (tid<64)
    float o[4][4];
    #pragma unroll
    for (int i = 0; i < 4; i++)
        #pragma unroll
        for (int j = 0; j < 4; j++) o[i][j] = 0.f;

    int ty = tid >> 4, tx = tid & 15;

    for (int kt = 0; kt <= qt; ++kt) {
        __syncthreads();
        {   // load K (transposed) and V (natural) tiles
            int t  = tid >> 2;
            int dq = (tid & 3) << 4;
            const float* kp = Kg + headoff + (size_t)(kt * 64 + t) * C + dq;
            const float* vp = Vg + headoff + (size_t)(kt * 64 + t) * C + dq;
            #pragma unroll
            for (int j = 0; j < 4; j++) {
                float4 v4 = *(const float4*)(kp + 4 * j);
                Ks[dq + 4 * j + 0][t] = v4.x;
                Ks[dq + 4 * j + 1][t] = v4.y;
                Ks[dq + 4 * j + 2][t] = v4.z;
                Ks[dq + 4 * j + 3][t] = v4.w;
                float4 w4 = *(const float4*)(vp + 4 * j);
                *(float4*)&Vs[t][dq + 4 * j] = w4;
            }
        }
        __syncthreads();

        float s[4][4];
        #pragma unroll
        for (int i = 0; i < 4; i++)
            #pragma unroll
            for (int j = 0; j < 4; j++) s[i][j] = 0.f;

        #pragma unroll 8
        for (int d = 0; d < 64; ++d) {
            float4 qa = *(const float4*)&Qs[d][ty * 4];
            float4 kb = *(const float4*)&Ks[d][tx * 4];
            float qv[4] = {qa.x, qa.y, qa.z, qa.w};
            float kv[4] = {kb.x, kb.y, kb.z, kb.w};
            #pragma unroll
            for (int i = 0; i < 4; i++)
                #pragma unroll
                for (int j = 0; j < 4; j++)
                    s[i][j] = fmaf(qv[i], kv[j], s[i][j]);
        }
        if (kt == qt) {
            #pragma unroll
            for (int i = 0; i < 4; i++)
                #pragma unroll
                for (int j = 0; j < 4; j++)
                    if (tx * 4 + j > ty * 4 + i) s[i][j] = -1e30f;
        }
        #pragma unroll
        for (int i = 0; i < 4; i++)
            #pragma unroll
            for (int j = 0; j < 4; j++)
                Ps[tx * 4 + j][ty * 4 + i] = s[i][j];
        __syncthreads();

        if (tid < 64) {
            int r = tid;
            float tm = -1e30f;
            for (int c = 0; c < 64; c++) tm = fmaxf(tm, Ps[c][r]);
            float mn = fmaxf(m, tm);
            float a  = __expf(m - mn);
            float sp = 0.f, sp2 = 0.f;
            for (int c = 0; c < 64; c++) {
                float pv = __expf(Ps[c][r] - mn);
                Ps[c][r] = pv;
                sp += pv; sp2 += pv * pv;
            }
            l  = l * a + sp;
            s2 = s2 * a * a + sp2;
            m  = mn;
            alphaS[r] = a;
        }
        __syncthreads();

        float av[4];
        #pragma unroll
        for (int i = 0; i < 4; i++) av[i] = alphaS[ty * 4 + i];
        #pragma unroll
        for (int i = 0; i < 4; i++)
            #pragma unroll
            for (int j = 0; j < 4; j++) o[i][j] *= av[i];

        #pragma unroll 8
        for (int c = 0; c < 64; ++c) {
            float4 pa = *(const float4*)&Ps[c][ty * 4];
            float4 vb = *(const float4*)&Vs[c][tx * 4];
            float pv[4] = {pa.x, pa.y, pa.z, pa.w};
            float vv[4] = {vb.x, vb.y, vb.z, vb.w};
            #pragma unroll
            for (int i = 0; i < 4; i++)
                #pragma unroll
                for (int j = 0; j < 4; j++)
                    o[i][j] = fmaf(pv[i], vv[j], o[i][j]);
        }
    }

    if (tid < 64) {
        linvS[tid] = 1.f / l;
        float e = s2 / (l * l);
        #pragma unroll
        for (int off = 32; off > 0; off >>= 1) e += __shfl_xor(e, off);
        if (tid == 0) atomicAdd(&He[b * NHEAD + h], (double)e);
    }
    __syncthreads();

    #pragma unroll
    for (int i = 0; i < 4; i++) {
        float inv = linvS[ty * 4 + i];
        float4 ov;
        ov.x = o[i][0] * inv; ov.y = o[i][1] * inv;
        ov.z = o[i][2] * inv; ov.w = o[i][3] * inv;
        *(float4*)(Ctx + headoff + (size_t)(qt * 64 + ty * 4 + i) * C + tx * 4) = ov;
    }
}

// ---------------------------------------------------------------------------
// Per-batch head selection: softmax over head energies -> entropy -> keep_h
// (round half to even) -> threshold -> 0/1 mask.
// ---------------------------------------------------------------------------
__global__ void headsel(const double* __restrict__ He, float* __restrict__ Mask)
{
    int b = threadIdx.x;
    if (b >= BATCH) return;
    double e[NHEAD];
    double mx = -1e300;
    for (int h = 0; h < NHEAD; h++) {
        e[h] = He[b * NHEAD + h] / (1024.0 * 1024.0);
        mx = fmax(mx, e[h]);
    }
    double p[NHEAD], s = 0.0;
    for (int h = 0; h < NHEAD; h++) { p[h] = exp(e[h] - mx); s += p[h]; }
    double ent = 0.0;
    for (int h = 0; h < NHEAD; h++) {
        double ph = p[h] / s;
        ent -= ph * log(ph + 1e-9);
    }
    double entn = ent / log(16.0);
    entn = fmin(fmax(entn, 0.0), 1.0);
    int keep = (int)rint(2.0 + entn * 4.0);
    if (keep < 1) keep = 1;
    if (keep > NHEAD) keep = NHEAD;
    double srt[NHEAD];
    for (int h = 0; h < NHEAD; h++) srt[h] = e[h];
    for (int i = 1; i < NHEAD; i++) {          // insertion sort, descending
        double v = srt[i]; int j = i - 1;
        while (j >= 0 && srt[j] < v) { srt[j + 1] = srt[j]; j--; }
        srt[j + 1] = v;
    }
    double th = srt[keep - 1];
    for (int h = 0; h < NHEAD; h++)
        Mask[b * NHEAD + h] = (e[h] >= th) ? 1.0f : 0.0f;
}

// ---------------------------------------------------------------------------
extern "C" void kernel_launch(void* const* d_in, const int* in_sizes, int n_in,
                              void* d_out, int out_size, void* d_ws, size_t ws_size,
                              hipStream_t stream)
{
    (void)in_sizes; (void)n_in; (void)out_size; (void)ws_size;
    const float* x  = (const float*)d_in[0];
    const float* qw = (const float*)d_in[1];
    const float* qb = (const float*)d_in[2];
    const float* kw = (const float*)d_in[3];
    const float* kb = (const float*)d_in[4];
    const float* vw = (const float*)d_in[5];
    const float* vb = (const float*)d_in[6];
    const float* ow = (const float*)d_in[7];
    const float* ob = (const float*)d_in[8];
    float* out = (float*)d_out;

    const size_t MK = (size_t)BATCH * T_SEQ * D_MODEL;   // 4M floats
    float*  q    = (float*)d_ws;
    float*  k    = q + MK;
    float*  v    = k + MK;
    float*  ctx  = v + MK;
    double* he   = (double*)(ctx + MK);     // byte offset 64MB: 8B-aligned
    float*  mask = (float*)(he + 64);

    hipMemsetAsync(he, 0, 64 * sizeof(double), stream);

    // q projection (f64 accumulation: top-k rank stability vs f64 gold)
    gemm_sign_f64<<<dim3(16, 64), 256, 0, stream>>>(x, qw, qb, q);
    // k, v projections (f32)
    gemm_bt<<<dim3(8, 32, 2), 256, 0, stream>>>(x, kw, vw, kb, vb, k, v,
                                                nullptr);
    normqk<<<dim3(16384, 2), 256, 0, stream>>>(q, k);
    attn_kernel<<<dim3(16, 16, 4), 256, 0, stream>>>(q, k, v, ctx, he);
    headsel<<<1, 64, 0, stream>>>(he, mask);
    // out projection with head-mask folded into A columns
    gemm_bt<<<dim3(8, 32, 1), 256, 0, stream>>>(ctx, ow, ow, ob, ob,
                                                out, out, mask);
}

// Round 3
// 781.529 us; speedup vs baseline: 1.2588x; 1.2588x over previous
//
#include <hip/hip_runtime.h>
#include <math.h>

#define D_MODEL 1024
#define T_SEQ   1024
#define BATCH   4
#define NHEAD   16
#define HDIM    64

// keep counts: trunc(linspace(0.35,0.15,16)*64), min 1
__constant__ int KEEPC[16] = {22,21,20,19,18,18,17,16,15,14,13,13,12,11,10,9};

typedef short bh8 __attribute__((ext_vector_type(8)));
typedef float f32x4 __attribute__((ext_vector_type(4)));

__device__ __forceinline__ unsigned short f2bf(float f) {
    unsigned int u = __float_as_uint(f);
    return (unsigned short)((u + 0x7FFFu + ((u >> 16) & 1u)) >> 16);
}
__device__ __forceinline__ float bf2f(unsigned short h) {
    return __uint_as_float(((unsigned int)h) << 16);
}

// ---------------------------------------------------------------------------
// Cast weights once: kw -> (hi,lo) bf16 split; vw, ow -> single bf16.
// ---------------------------------------------------------------------------
__global__ void cast_weights(const float* __restrict__ kw,
                             unsigned short* __restrict__ kwh,
                             unsigned short* __restrict__ kwl,
                             const float* __restrict__ vw,
                             unsigned short* __restrict__ vwb,
                             const float* __restrict__ ow,
                             unsigned short* __restrict__ owb)
{
    const int NS = (D_MODEL * D_MODEL) / 8;    // 131072 slots of 8 elems
    int i = blockIdx.x * 256 + threadIdx.x;
    const float* src; unsigned short* dh; unsigned short* dl = nullptr;
    long off;
    if (i < NS)           { src = kw; dh = kwh; dl = kwl; off = i; }
    else if (i < 2 * NS)  { src = vw; dh = vwb; off = i - NS; }
    else if (i < 3 * NS)  { src = ow; dh = owb; off = i - 2 * NS; }
    else return;
    long e = off * 8;
    alignas(16) float fl[8];
    *(float4*)&fl[0] = *(const float4*)(src + e);
    *(float4*)&fl[4] = *(const float4*)(src + e + 4);
    uint4 hp, lp;
    unsigned int* hpw = (unsigned int*)&hp;
    unsigned int* lpw = (unsigned int*)&lp;
    #pragma unroll
    for (int c = 0; c < 4; c++) {
        unsigned short h0 = f2bf(fl[2 * c]), h1 = f2bf(fl[2 * c + 1]);
        hpw[c] = (unsigned int)h0 | ((unsigned int)h1 << 16);
        if (dl) {
            unsigned short l0 = f2bf(fl[2 * c] - bf2f(h0));
            unsigned short l1 = f2bf(fl[2 * c + 1] - bf2f(h1));
            lpw[c] = (unsigned int)l0 | ((unsigned int)l1 << 16);
        }
    }
    *(uint4*)(dh + e) = hp;
    if (dl) *(uint4*)(dl + e) = lp;
}

// ---------------------------------------------------------------------------
// Q projection with float64 accumulation (unchanged numerics from the passing
// round): top-k rank stability requires matching the f64 numpy gold.
// ---------------------------------------------------------------------------
__global__ __launch_bounds__(256, 3) void gemm_sign_f64(
    const float* __restrict__ A, const float* __restrict__ W,
    const float* __restrict__ Bi, float* __restrict__ Y)
{
    const int K = D_MODEL, N = D_MODEL;
    __shared__ float As[16][68];
    __shared__ float Ws[16][68];

    int tid  = threadIdx.x;
    int bm   = blockIdx.y * 64;
    int bn   = blockIdx.x * 64;
    int lrow = tid >> 2;
    int lk   = (tid & 3) * 4;
    int ty   = tid >> 4;
    int tx   = tid & 15;

    double acc[4][4];
    #pragma unroll
    for (int i = 0; i < 4; i++)
        #pragma unroll
        for (int j = 0; j < 4; j++) acc[i][j] = 0.0;

    const float* aptr = A + (size_t)(bm + lrow) * K + lk;
    const float* wptr = W + (size_t)(bn + lrow) * K + lk;

    for (int k0 = 0; k0 < K; k0 += 16) {
        float4 a4 = *(const float4*)aptr;
        float4 w4 = *(const float4*)wptr;
        aptr += 16; wptr += 16;
        w4.x = (float)((w4.x > 0.f) - (w4.x < 0.f));
        w4.y = (float)((w4.y > 0.f) - (w4.y < 0.f));
        w4.z = (float)((w4.z > 0.f) - (w4.z < 0.f));
        w4.w = (float)((w4.w > 0.f) - (w4.w < 0.f));

        __syncthreads();
        As[lk + 0][lrow] = a4.x; As[lk + 1][lrow] = a4.y;
        As[lk + 2][lrow] = a4.z; As[lk + 3][lrow] = a4.w;
        Ws[lk + 0][lrow] = w4.x; Ws[lk + 1][lrow] = w4.y;
        Ws[lk + 2][lrow] = w4.z; Ws[lk + 3][lrow] = w4.w;
        __syncthreads();

        #pragma unroll
        for (int kk = 0; kk < 16; kk += 4) {
            float p[4][4];
            #pragma unroll
            for (int i = 0; i < 4; i++)
                #pragma unroll
                for (int j = 0; j < 4; j++) p[i][j] = 0.f;
            #pragma unroll
            for (int t = 0; t < 4; t++) {
                alignas(16) float av[4], wv[4];
                *(float4*)av = *(const float4*)&As[kk + t][ty * 4];
                *(float4*)wv = *(const float4*)&Ws[kk + t][tx * 4];
                #pragma unroll
                for (int i = 0; i < 4; i++)
                    #pragma unroll
                    for (int j = 0; j < 4; j++)
                        p[i][j] = fmaf(av[i], wv[j], p[i][j]);
            }
            #pragma unroll
            for (int i = 0; i < 4; i++)
                #pragma unroll
                for (int j = 0; j < 4; j++)
                    acc[i][j] += (double)p[i][j];
        }
    }

    #pragma unroll
    for (int i = 0; i < 4; i++) {
        float* yp = Y + (size_t)(bm + ty * 4 + i) * N + bn + tx * 4;
        const float* bp = Bi + bn + tx * 4;
        float4 o;
        o.x = (float)acc[i][0] + bp[0];
        o.y = (float)acc[i][1] + bp[1];
        o.z = (float)acc[i][2] + bp[2];
        o.w = (float)acc[i][3] + bp[3];
        *(float4*)yp = o;
    }
}

// ---------------------------------------------------------------------------
// MFMA GEMM with on-the-fly bf16 split of fp32 A: Y = A @ W^T + bias.
// split=1: W given as (hi,lo) pair, A split into hi+lo, 3 MFMA passes ->
// fp32-quality product (error ~2^-18 rel). split=0: single bf16 pass.
// 128x128 tile, BK=64, 256 threads, 4 waves each 64x64 via 16x16x32 mfma.
// ---------------------------------------------------------------------------
#define GLDK 72   // padded bf16 per LDS row (64 + 8)

__global__ __launch_bounds__(256, 2) void gemm_xsplit(
    const float* __restrict__ A, const unsigned short* __restrict__ Wh,
    const unsigned short* __restrict__ Wl, const float* __restrict__ Bi,
    float* __restrict__ Y, int split)
{
    __shared__ unsigned short Ah[128 * GLDK];
    __shared__ unsigned short Al[128 * GLDK];
    __shared__ unsigned short Whs[128 * GLDK];
    __shared__ unsigned short Wls[128 * GLDK];

    int tid  = threadIdx.x;
    int bm   = blockIdx.y * 128, bn = blockIdx.x * 128;
    int wave = tid >> 6, lane = tid & 63;
    int l15  = lane & 15, q4 = lane >> 4;
    int wm   = (wave >> 1) * 64, wn = (wave & 1) * 64;
    int srow = tid >> 1;
    int scol = (tid & 1) * 32;

    f32x4 acc[4][4];
    #pragma unroll
    for (int i = 0; i < 4; i++)
        #pragma unroll
        for (int j = 0; j < 4; j++) acc[i][j] = (f32x4)0.f;

    const float* ap = A + (size_t)(bm + srow) * D_MODEL + scol;
    const unsigned short* whp = Wh + (size_t)(bn + srow) * D_MODEL + scol;
    const unsigned short* wlp = (split ? Wl : Wh) + (size_t)(bn + srow) * D_MODEL + scol;

    for (int k0 = 0; k0 < D_MODEL; k0 += 64) {
        alignas(16) float fl[32];
        #pragma unroll
        for (int c = 0; c < 8; c++) *(float4*)&fl[4 * c] = *(const float4*)(ap + 4 * c);
        uint4 w0 = *(const uint4*)(whp + 0),  w1 = *(const uint4*)(whp + 8);
        uint4 w2 = *(const uint4*)(whp + 16), w3 = *(const uint4*)(whp + 24);
        uint4 x0, x1, x2, x3;
        if (split) {
            x0 = *(const uint4*)(wlp + 0);  x1 = *(const uint4*)(wlp + 8);
            x2 = *(const uint4*)(wlp + 16); x3 = *(const uint4*)(wlp + 24);
        }
        ap += 64; whp += 64; wlp += 64;

        unsigned int hw[16], lw[16];
        #pragma unroll
        for (int c = 0; c < 16; c++) {
            unsigned short h0 = f2bf(fl[2 * c]), h1 = f2bf(fl[2 * c + 1]);
            hw[c] = (unsigned int)h0 | ((unsigned int)h1 << 16);
            if (split) {
                unsigned short l0 = f2bf(fl[2 * c] - bf2f(h0));
                unsigned short l1 = f2bf(fl[2 * c + 1] - bf2f(h1));
                lw[c] = (unsigned int)l0 | ((unsigned int)l1 << 16);
            }
        }

        __syncthreads();
        unsigned int* ah = (unsigned int*)&Ah[srow * GLDK + scol];
        #pragma unroll
        for (int g = 0; g < 4; g++)
            *(uint4*)(ah + 4 * g) = make_uint4(hw[4 * g], hw[4 * g + 1], hw[4 * g + 2], hw[4 * g + 3]);
        if (split) {
            unsigned int* al = (unsigned int*)&Al[srow * GLDK + scol];
            #pragma unroll
            for (int g = 0; g < 4; g++)
                *(uint4*)(al + 4 * g) = make_uint4(lw[4 * g], lw[4 * g + 1], lw[4 * g + 2], lw[4 * g + 3]);
        }
        unsigned short* ws = &Whs[srow * GLDK + scol];
        *(uint4*)(ws + 0) = w0; *(uint4*)(ws + 8)  = w1;
        *(uint4*)(ws + 16) = w2; *(uint4*)(ws + 24) = w3;
        if (split) {
            unsigned short* wl2 = &Wls[srow * GLDK + scol];
            *(uint4*)(wl2 + 0) = x0; *(uint4*)(wl2 + 8)  = x1;
            *(uint4*)(wl2 + 16) = x2; *(uint4*)(wl2 + 24) = x3;
        }
        __syncthreads();

        #pragma unroll
        for (int kc = 0; kc < 64; kc += 32) {
            bh8 ahf[4], whf[4];
            #pragma unroll
            for (int i = 0; i < 4; i++)
                ahf[i] = *(bh8*)&Ah[(wm + i * 16 + l15) * GLDK + kc + q4 * 8];
            #pragma unroll
            for (int j = 0; j < 4; j++)
                whf[j] = *(bh8*)&Whs[(wn + j * 16 + l15) * GLDK + kc + q4 * 8];
            #pragma unroll
            for (int i = 0; i < 4; i++)
                #pragma unroll
                for (int j = 0; j < 4; j++)
                    acc[i][j] = __builtin_amdgcn_mfma_f32_16x16x32_bf16(ahf[i], whf[j], acc[i][j], 0, 0, 0);
            if (split) {
                bh8 alf[4], wlf[4];
                #pragma unroll
                for (int i = 0; i < 4; i++)
                    alf[i] = *(bh8*)&Al[(wm + i * 16 + l15) * GLDK + kc + q4 * 8];
                #pragma unroll
                for (int j = 0; j < 4; j++)
                    wlf[j] = *(bh8*)&Wls[(wn + j * 16 + l15) * GLDK + kc + q4 * 8];
                #pragma unroll
                for (int i = 0; i < 4; i++)
                    #pragma unroll
                    for (int j = 0; j < 4; j++) {
                        acc[i][j] = __builtin_amdgcn_mfma_f32_16x16x32_bf16(ahf[i], wlf[j], acc[i][j], 0, 0, 0);
                        acc[i][j] = __builtin_amdgcn_mfma_f32_16x16x32_bf16(alf[i], whf[j], acc[i][j], 0, 0, 0);
                    }
            }
        }
    }

    #pragma unroll
    for (int j = 0; j < 4; j++) {
        int col = bn + wn + j * 16 + l15;
        float bv = Bi[col];
        #pragma unroll
        for (int i = 0; i < 4; i++) {
            int row = bm + wm + i * 16 + q4 * 4;
            #pragma unroll
            for (int r = 0; r < 4; r++)
                Y[(size_t)(row + r) * D_MODEL + col] = acc[i][j][r] + bv;
        }
    }
}

// ---------------------------------------------------------------------------
// Out-projection: bf16 A (ctx) @ bf16 W^T + bias, head mask folded into A.
// ---------------------------------------------------------------------------
__global__ __launch_bounds__(256, 2) void gemm_obf(
    const unsigned short* __restrict__ A, const unsigned short* __restrict__ W,
    const float* __restrict__ Bi, float* __restrict__ Y,
    const float* __restrict__ amask)
{
    __shared__ unsigned short As[128 * GLDK];
    __shared__ unsigned short Ws[128 * GLDK];

    int tid  = threadIdx.x;
    int bm   = blockIdx.y * 128, bn = blockIdx.x * 128;
    int wave = tid >> 6, lane = tid & 63;
    int l15  = lane & 15, q4 = lane >> 4;
    int wm   = (wave >> 1) * 64, wn = (wave & 1) * 64;
    int srow = tid >> 1;
    int scol = (tid & 1) * 32;
    int batch = bm >> 10;

    f32x4 acc[4][4];
    #pragma unroll
    for (int i = 0; i < 4; i++)
        #pragma unroll
        for (int j = 0; j < 4; j++) acc[i][j] = (f32x4)0.f;

    const unsigned short* ap = A + (size_t)(bm + srow) * D_MODEL + scol;
    const unsigned short* wp = W + (size_t)(bn + srow) * D_MODEL + scol;

    for (int k0 = 0; k0 < D_MODEL; k0 += 64) {
        uint4 a0 = *(const uint4*)(ap + 0),  a1 = *(const uint4*)(ap + 8);
        uint4 a2 = *(const uint4*)(ap + 16), a3 = *(const uint4*)(ap + 24);
        uint4 w0 = *(const uint4*)(wp + 0),  w1 = *(const uint4*)(wp + 8);
        uint4 w2 = *(const uint4*)(wp + 16), w3 = *(const uint4*)(wp + 24);
        ap += 64; wp += 64;
        if (amask[batch * NHEAD + (k0 >> 6)] == 0.f) {
            a0 = a1 = a2 = a3 = make_uint4(0, 0, 0, 0);
        }
        __syncthreads();
        unsigned short* as = &As[srow * GLDK + scol];
        *(uint4*)(as + 0) = a0; *(uint4*)(as + 8)  = a1;
        *(uint4*)(as + 16) = a2; *(uint4*)(as + 24) = a3;
        unsigned short* ws = &Ws[srow * GLDK + scol];
        *(uint4*)(ws + 0) = w0; *(uint4*)(ws + 8)  = w1;
        *(uint4*)(ws + 16) = w2; *(uint4*)(ws + 24) = w3;
        __syncthreads();

        #pragma unroll
        for (int kc = 0; kc < 64; kc += 32) {
            bh8 af[4], wf[4];
            #pragma unroll
            for (int i = 0; i < 4; i++)
                af[i] = *(bh8*)&As[(wm + i * 16 + l15) * GLDK + kc + q4 * 8];
            #pragma unroll
            for (int j = 0; j < 4; j++)
                wf[j] = *(bh8*)&Ws[(wn + j * 16 + l15) * GLDK + kc + q4 * 8];
            #pragma unroll
            for (int i = 0; i < 4; i++)
                #pragma unroll
                for (int j = 0; j < 4; j++)
                    acc[i][j] = __builtin_amdgcn_mfma_f32_16x16x32_bf16(af[i], wf[j], acc[i][j], 0, 0, 0);
        }
    }

    #pragma unroll
    for (int j = 0; j < 4; j++) {
        int col = bn + wn + j * 16 + l15;
        float bv = Bi[col];
        #pragma unroll
        for (int i = 0; i < 4; i++) {
            int row = bm + wm + i * 16 + q4 * 4;
            #pragma unroll
            for (int r = 0; r < 4; r++)
                Y[(size_t)(row + r) * D_MODEL + col] = acc[i][j][r] + bv;
        }
    }
}

// ---------------------------------------------------------------------------
// RMS-normalize rows of 64 (per b,t,head). y==0: q (norm + top-k), y==1: k.
// ---------------------------------------------------------------------------
__global__ void normqk(float* __restrict__ Q, float* __restrict__ Kb)
{
    int tid  = threadIdx.x;
    int wid  = tid >> 6;
    int lane = tid & 63;
    long rid = (long)blockIdx.x * 4 + wid;
    int isK  = blockIdx.y;
    int h    = (int)(rid & 15);
    long bt  = rid >> 4;

    float* p = (isK ? Kb : Q) + bt * D_MODEL + h * HDIM;
    float x = p[lane];
    float ss = x * x;
    #pragma unroll
    for (int off = 32; off > 0; off >>= 1) ss += __shfl_xor(ss, off);
    float rms = sqrtf(ss * (1.0f / 64.0f));
    float xn = x / (rms + 1e-6f);

    if (!isK) {
        float a = fabsf(xn);
        int cnt = 0;
        for (int j = 0; j < 64; j++) {
            float o = __shfl(a, j);
            cnt += (o > a) ? 1 : 0;
        }
        if (cnt >= KEEPC[h]) xn = 0.f;
    }
    p[lane] = xn;
}

// ---------------------------------------------------------------------------
// Flash-style causal attention per (b,h,q-tile of 64), fp32, distributed
// softmax (shfl row reductions), P aliased onto the K LDS tile, heavy-first
// qt order. Emits ctx as bf16 and sum(attn^2) per head (f64 atomics).
// ---------------------------------------------------------------------------
#define APAD 68
__global__ __launch_bounds__(256, 3) void attn_kernel(
    const float* __restrict__ Qg, const float* __restrict__ Kg,
    const float* __restrict__ Vg, unsigned short* __restrict__ Ctx,
    double* __restrict__ He)
{
    __shared__ float Qs[64][APAD];    // [d][r]
    __shared__ float KPs[64][APAD];   // K phase: [d][c]; P phase: [r][c]
    __shared__ float Vs[64][APAD];    // [c][d]

    int tid = threadIdx.x;
    int qt = 15 - (int)blockIdx.x;    // heavy blocks dispatch first
    int h = blockIdx.y, b = blockIdx.z;
    size_t headoff = (size_t)b * T_SEQ * D_MODEL + h * HDIM;

    {   // load Q tile transposed [d][r]
        int t  = tid >> 2;
        int dq = (tid & 3) << 4;
        const float* qp = Qg + headoff + (size_t)(qt * 64 + t) * D_MODEL + dq;
        #pragma unroll
        for (int j = 0; j < 4; j++) {
            float4 v4 = *(const float4*)(qp + 4 * j);
            Qs[dq + 4 * j + 0][t] = v4.x;
            Qs[dq + 4 * j + 1][t] = v4.y;
            Qs[dq + 4 * j + 2][t] = v4.z;
            Qs[dq + 4 * j + 3][t] = v4.w;
        }
    }

    int ty = tid >> 4, tx = tid & 15;   // rows ty*4+i, cols tx*4+j
    float m[4], l[4], s2[4];
    #pragma unroll
    for (int i = 0; i < 4; i++) { m[i] = -1e30f; l[i] = 0.f; s2[i] = 0.f; }
    float o[4][4];
    #pragma unroll
    for (int i = 0; i < 4; i++)
        #pragma unroll
        for (int j = 0; j < 4; j++) o[i][j] = 0.f;

    for (int kt = 0; kt <= qt; ++kt) {
        __syncthreads();   // prior PV reads of KPs/Vs complete
        {   // load K transposed [d][c], V natural [c][d]
            int t  = tid >> 2;
            int dq = (tid & 3) << 4;
            const float* kp = Kg + headoff + (size_t)(kt * 64 + t) * D_MODEL + dq;
            const float* vp = Vg + headoff + (size_t)(kt * 64 + t) * D_MODEL + dq;
            #pragma unroll
            for (int j = 0; j < 4; j++) {
                float4 v4 = *(const float4*)(kp + 4 * j);
                KPs[dq + 4 * j + 0][t] = v4.x;
                KPs[dq + 4 * j + 1][t] = v4.y;
                KPs[dq + 4 * j + 2][t] = v4.z;
                KPs[dq + 4 * j + 3][t] = v4.w;
                float4 w4 = *(const float4*)(vp + 4 * j);
                *(float4*)&Vs[t][dq + 4 * j] = w4;
            }
        }
        __syncthreads();

        float s[4][4];
        #pragma unroll
        for (int i = 0; i < 4; i++)
            #pragma unroll
            for (int j = 0; j < 4; j++) s[i][j] = 0.f;

        #pragma unroll 8
        for (int d = 0; d < 64; ++d) {
            float4 qa = *(const float4*)&Qs[d][ty * 4];
            float4 kb = *(const float4*)&KPs[d][tx * 4];
            float qv[4] = {qa.x, qa.y, qa.z, qa.w};
            float kv[4] = {kb.x, kb.y, kb.z, kb.w};
            #pragma unroll
            for (int i = 0; i < 4; i++)
                #pragma unroll
                for (int j = 0; j < 4; j++)
                    s[i][j] = fmaf(qv[i], kv[j], s[i][j]);
        }
        if (kt == qt) {
            #pragma unroll
            for (int i = 0; i < 4; i++)
                #pragma unroll
                for (int j = 0; j < 4; j++)
                    if (tx * 4 + j > ty * 4 + i) s[i][j] = -1e30f;
        }

        // distributed online softmax: reduce across the 16 lanes (tx) that
        // share a row group (lane bits 0..3).
        float al[4];
        #pragma unroll
        for (int i = 0; i < 4; i++) {
            float rm = fmaxf(fmaxf(s[i][0], s[i][1]), fmaxf(s[i][2], s[i][3]));
            #pragma unroll
            for (int off = 1; off < 16; off <<= 1) rm = fmaxf(rm, __shfl_xor(rm, off));
            float mn = fmaxf(m[i], rm);
            al[i] = __expf(m[i] - mn);
            m[i] = mn;
            float rs = 0.f, rs2 = 0.f;
            #pragma unroll
            for (int j = 0; j < 4; j++) {
                float pv = __expf(s[i][j] - mn);
                s[i][j] = pv;
                rs += pv; rs2 += pv * pv;
            }
            #pragma unroll
            for (int off = 1; off < 16; off <<= 1) {
                rs  += __shfl_xor(rs, off);
                rs2 += __shfl_xor(rs2, off);
            }
            l[i]  = l[i] * al[i] + rs;
            s2[i] = s2[i] * al[i] * al[i] + rs2;
        }

        __syncthreads();   // all S-phase reads of KPs done
        #pragma unroll
        for (int i = 0; i < 4; i++)
            *(float4*)&KPs[ty * 4 + i][tx * 4] = make_float4(s[i][0], s[i][1], s[i][2], s[i][3]);
        __syncthreads();

        #pragma unroll
        for (int i = 0; i < 4; i++)
            #pragma unroll
            for (int j = 0; j < 4; j++) o[i][j] *= al[i];

        #pragma unroll 4
        for (int c4 = 0; c4 < 64; c4 += 4) {
            float4 pa[4], vb[4];
            #pragma unroll
            for (int i = 0; i < 4; i++) pa[i] = *(const float4*)&KPs[ty * 4 + i][c4];   // broadcast
            #pragma unroll
            for (int cc = 0; cc < 4; cc++) vb[cc] = *(const float4*)&Vs[c4 + cc][tx * 4];
            #pragma unroll
            for (int i = 0; i < 4; i++) {
                float pv[4] = {pa[i].x, pa[i].y, pa[i].z, pa[i].w};
                #pragma unroll
                for (int cc = 0; cc < 4; cc++) {
                    float vv[4] = {vb[cc].x, vb[cc].y, vb[cc].z, vb[cc].w};
                    #pragma unroll
                    for (int j = 0; j < 4; j++)
                        o[i][j] = fmaf(pv[cc], vv[j], o[i][j]);
                }
            }
        }
    }

    float linv[4];
    #pragma unroll
    for (int i = 0; i < 4; i++) linv[i] = 1.f / l[i];

    float e = 0.f;
    if (tx == 0) {
        #pragma unroll
        for (int i = 0; i < 4; i++) e += s2[i] * linv[i] * linv[i];
    }
    #pragma unroll
    for (int off = 1; off < 64; off <<= 1) e += __shfl_xor(e, off);
    if ((tid & 63) == 0) atomicAdd(&He[b * NHEAD + h], (double)e);

    #pragma unroll
    for (int i = 0; i < 4; i++) {
        int row = qt * 64 + ty * 4 + i;
        uint2 u;
        u.x = (unsigned int)f2bf(o[i][0] * linv[i]) | ((unsigned int)f2bf(o[i][1] * linv[i]) << 16);
        u.y = (unsigned int)f2bf(o[i][2] * linv[i]) | ((unsigned int)f2bf(o[i][3] * linv[i]) << 16);
        *(uint2*)(Ctx + headoff + (size_t)row * D_MODEL + tx * 4) = u;
    }
}

// ---------------------------------------------------------------------------
// Per-batch head selection (unchanged).
// ---------------------------------------------------------------------------
__global__ void headsel(const double* __restrict__ He, float* __restrict__ Mask)
{
    int b = threadIdx.x;
    if (b >= BATCH) return;
    double e[NHEAD];
    double mx = -1e300;
    for (int h = 0; h < NHEAD; h++) {
        e[h] = He[b * NHEAD + h] / (1024.0 * 1024.0);
        mx = fmax(mx, e[h]);
    }
    double p[NHEAD], s = 0.0;
    for (int h = 0; h < NHEAD; h++) { p[h] = exp(e[h] - mx); s += p[h]; }
    double ent = 0.0;
    for (int h = 0; h < NHEAD; h++) {
        double ph = p[h] / s;
        ent -= ph * log(ph + 1e-9);
    }
    double entn = ent / log(16.0);
    entn = fmin(fmax(entn, 0.0), 1.0);
    int keep = (int)rint(2.0 + entn * 4.0);
    if (keep < 1) keep = 1;
    if (keep > NHEAD) keep = NHEAD;
    double srt[NHEAD];
    for (int h = 0; h < NHEAD; h++) srt[h] = e[h];
    for (int i = 1; i < NHEAD; i++) {
        double v = srt[i]; int j = i - 1;
        while (j >= 0 && srt[j] < v) { srt[j + 1] = srt[j]; j--; }
        srt[j + 1] = v;
    }
    double th = srt[keep - 1];
    for (int h = 0; h < NHEAD; h++)
        Mask[b * NHEAD + h] = (e[h] >= th) ? 1.0f : 0.0f;
}

// ---------------------------------------------------------------------------
extern "C" void kernel_launch(void* const* d_in, const int* in_sizes, int n_in,
                              void* d_out, int out_size, void* d_ws, size_t ws_size,
                              hipStream_t stream)
{
    (void)in_sizes; (void)n_in; (void)out_size; (void)ws_size;
    const float* x  = (const float*)d_in[0];
    const float* qw = (const float*)d_in[1];
    const float* qb = (const float*)d_in[2];
    const float* kw = (const float*)d_in[3];
    const float* kb = (const float*)d_in[4];
    const float* vw = (const float*)d_in[5];
    const float* vb = (const float*)d_in[6];
    const float* ow = (const float*)d_in[7];
    const float* ob = (const float*)d_in[8];
    float* out = (float*)d_out;

    char* base = (char*)d_ws;
    const size_t MB16 = (size_t)16 * 1024 * 1024;
    float*          q    = (float*)(base);
    float*          k    = (float*)(base + MB16);
    float*          v    = (float*)(base + 2 * MB16);
    unsigned short* ctxb = (unsigned short*)(base + 3 * MB16);            // 8 MB
    unsigned short* kwh  = (unsigned short*)(base + 3 * MB16 + (MB16 >> 1));          // 2 MB
    unsigned short* kwl  = (unsigned short*)(base + 3 * MB16 + (MB16 >> 1) + 2097152);
    unsigned short* vwb  = (unsigned short*)(base + 3 * MB16 + (MB16 >> 1) + 2 * 2097152);
    unsigned short* owb  = (unsigned short*)(base + 3 * MB16 + (MB16 >> 1) + 3 * 2097152);
    double*         he   = (double*)(base + 4 * MB16);
    float*          mask = (float*)(base + 4 * MB16 + 512);

    hipMemsetAsync(he, 0, 64 * sizeof(double), stream);

    cast_weights<<<1536, 256, 0, stream>>>(kw, kwh, kwl, vw, vwb, ow, owb);
    // q projection: f64 accumulation (top-k rank stability)
    gemm_sign_f64<<<dim3(16, 64), 256, 0, stream>>>(x, qw, qb, q);
    // k projection: split-bf16 MFMA (fp32-quality), v: single-bf16 MFMA
    gemm_xsplit<<<dim3(8, 32), 256, 0, stream>>>(x, kwh, kwl, kb, k, 1);
    gemm_xsplit<<<dim3(8, 32), 256, 0, stream>>>(x, vwb, nullptr, vb, v, 0);
    normqk<<<dim3(16384, 2), 256, 0, stream>>>(q, k);
    attn_kernel<<<dim3(16, 16, 4), 256, 0, stream>>>(q, k, v, ctxb, he);
    headsel<<<1, 64, 0, stream>>>(he, mask);
    gemm_obf<<<dim3(8, 32), 256, 0, stream>>>(ctxb, owb, ob, out, mask);
}

// Round 4
// 555.112 us; speedup vs baseline: 1.7722x; 1.4079x over previous
//
#include <hip/hip_runtime.h>
#include <math.h>

#define D_MODEL 1024
#define T_SEQ   1024
#define BATCH   4
#define NHEAD   16
#define HDIM    64

// keep counts: trunc(linspace(0.35,0.15,16)*64), min 1
__constant__ int KEEPC[16] = {22,21,20,19,18,18,17,16,15,14,13,13,12,11,10,9};

typedef short bh8 __attribute__((ext_vector_type(8)));
typedef float f32x4 __attribute__((ext_vector_type(4)));

__device__ __forceinline__ unsigned short f2bf(float f) {
    unsigned int u = __float_as_uint(f);
    return (unsigned short)((u + 0x7FFFu + ((u >> 16) & 1u)) >> 16);
}
__device__ __forceinline__ float bf2f(unsigned short h) {
    return __uint_as_float(((unsigned int)h) << 16);
}

// ---------------------------------------------------------------------------
// Cast weights once: kw -> (hi,lo) bf16 split; vw, ow -> single bf16.
// ---------------------------------------------------------------------------
__global__ void cast_weights(const float* __restrict__ kw,
                             unsigned short* __restrict__ kwh,
                             unsigned short* __restrict__ kwl,
                             const float* __restrict__ vw,
                             unsigned short* __restrict__ vwb,
                             const float* __restrict__ ow,
                             unsigned short* __restrict__ owb)
{
    const int NS = (D_MODEL * D_MODEL) / 8;
    int i = blockIdx.x * 256 + threadIdx.x;
    const float* src; unsigned short* dh; unsigned short* dl = nullptr;
    long off;
    if (i < NS)           { src = kw; dh = kwh; dl = kwl; off = i; }
    else if (i < 2 * NS)  { src = vw; dh = vwb; off = i - NS; }
    else if (i < 3 * NS)  { src = ow; dh = owb; off = i - 2 * NS; }
    else return;
    long e = off * 8;
    alignas(16) float fl[8];
    *(float4*)&fl[0] = *(const float4*)(src + e);
    *(float4*)&fl[4] = *(const float4*)(src + e + 4);
    uint4 hp, lp;
    unsigned int* hpw = (unsigned int*)&hp;
    unsigned int* lpw = (unsigned int*)&lp;
    #pragma unroll
    for (int c = 0; c < 4; c++) {
        unsigned short h0 = f2bf(fl[2 * c]), h1 = f2bf(fl[2 * c + 1]);
        hpw[c] = (unsigned int)h0 | ((unsigned int)h1 << 16);
        if (dl) {
            unsigned short l0 = f2bf(fl[2 * c] - bf2f(h0));
            unsigned short l1 = f2bf(fl[2 * c + 1] - bf2f(h1));
            lpw[c] = (unsigned int)l0 | ((unsigned int)l1 << 16);
        }
    }
    *(uint4*)(dh + e) = hp;
    if (dl) *(uint4*)(dl + e) = lp;
}

// ---------------------------------------------------------------------------
// Q projection, f64 accumulation (top-k rank stability). Output written
// HEAD-MAJOR fp32: [(b*16+h)*1024 + t][d].
// ---------------------------------------------------------------------------
__global__ __launch_bounds__(256, 3) void gemm_sign_f64(
    const float* __restrict__ A, const float* __restrict__ W,
    const float* __restrict__ Bi, float* __restrict__ Y)
{
    const int K = D_MODEL;
    __shared__ float As[16][68];
    __shared__ float Ws[16][68];

    int tid  = threadIdx.x;
    int bm   = blockIdx.y * 64;
    int bn   = blockIdx.x * 64;
    int lrow = tid >> 2;
    int lk   = (tid & 3) * 4;
    int ty   = tid >> 4;
    int tx   = tid & 15;

    double acc[4][4];
    #pragma unroll
    for (int i = 0; i < 4; i++)
        #pragma unroll
        for (int j = 0; j < 4; j++) acc[i][j] = 0.0;

    const float* aptr = A + (size_t)(bm + lrow) * K + lk;
    const float* wptr = W + (size_t)(bn + lrow) * K + lk;

    for (int k0 = 0; k0 < K; k0 += 16) {
        float4 a4 = *(const float4*)aptr;
        float4 w4 = *(const float4*)wptr;
        aptr += 16; wptr += 16;
        w4.x = (float)((w4.x > 0.f) - (w4.x < 0.f));
        w4.y = (float)((w4.y > 0.f) - (w4.y < 0.f));
        w4.z = (float)((w4.z > 0.f) - (w4.z < 0.f));
        w4.w = (float)((w4.w > 0.f) - (w4.w < 0.f));

        __syncthreads();
        As[lk + 0][lrow] = a4.x; As[lk + 1][lrow] = a4.y;
        As[lk + 2][lrow] = a4.z; As[lk + 3][lrow] = a4.w;
        Ws[lk + 0][lrow] = w4.x; Ws[lk + 1][lrow] = w4.y;
        Ws[lk + 2][lrow] = w4.z; Ws[lk + 3][lrow] = w4.w;
        __syncthreads();

        #pragma unroll
        for (int kk = 0; kk < 16; kk += 4) {
            float p[4][4];
            #pragma unroll
            for (int i = 0; i < 4; i++)
                #pragma unroll
                for (int j = 0; j < 4; j++) p[i][j] = 0.f;
            #pragma unroll
            for (int t = 0; t < 4; t++) {
                alignas(16) float av[4], wv[4];
                *(float4*)av = *(const float4*)&As[kk + t][ty * 4];
                *(float4*)wv = *(const float4*)&Ws[kk + t][tx * 4];
                #pragma unroll
                for (int i = 0; i < 4; i++)
                    #pragma unroll
                    for (int j = 0; j < 4; j++)
                        p[i][j] = fmaf(av[i], wv[j], p[i][j]);
            }
            #pragma unroll
            for (int i = 0; i < 4; i++)
                #pragma unroll
                for (int j = 0; j < 4; j++)
                    acc[i][j] += (double)p[i][j];
        }
    }

    int colb = bn + tx * 4;          // 4 cols all inside one head
    int hh = colb >> 6, dd = colb & 63;
    #pragma unroll
    for (int i = 0; i < 4; i++) {
        int row = bm + ty * 4 + i;
        int bb = row >> 10, tt = row & 1023;
        float* yp = Y + (((size_t)(bb * NHEAD + hh)) * T_SEQ + tt) * HDIM + dd;
        const float* bp = Bi + colb;
        float4 o;
        o.x = (float)acc[i][0] + bp[0];
        o.y = (float)acc[i][1] + bp[1];
        o.z = (float)acc[i][2] + bp[2];
        o.w = (float)acc[i][3] + bp[3];
        *(float4*)yp = o;
    }
}

// ---------------------------------------------------------------------------
// MFMA GEMM, bf16 split of fp32 A on the fly.
// split=1 (k-proj): 3-pass hi/lo product, fp32 out HEAD-MAJOR into Yf.
// split=0 (v-proj): single bf16 pass, bf16 out TRANSPOSED head-major
//                   Yv[(b*16+h)*64 + d][t]  (V^T for attention B-operand).
// ---------------------------------------------------------------------------
#define GLDK 72

__global__ __launch_bounds__(256, 2) void gemm_xsplit(
    const float* __restrict__ A, const unsigned short* __restrict__ Wh,
    const unsigned short* __restrict__ Wl, const float* __restrict__ Bi,
    float* __restrict__ Yf, unsigned short* __restrict__ Yv, int split)
{
    __shared__ unsigned short Ah[128 * GLDK];
    __shared__ unsigned short Al[128 * GLDK];
    __shared__ unsigned short Whs[128 * GLDK];
    __shared__ unsigned short Wls[128 * GLDK];

    int tid  = threadIdx.x;
    int bm   = blockIdx.y * 128, bn = blockIdx.x * 128;
    int wave = tid >> 6, lane = tid & 63;
    int l15  = lane & 15, q4 = lane >> 4;
    int wm   = (wave >> 1) * 64, wn = (wave & 1) * 64;
    int srow = tid >> 1;
    int scol = (tid & 1) * 32;

    f32x4 acc[4][4];
    #pragma unroll
    for (int i = 0; i < 4; i++)
        #pragma unroll
        for (int j = 0; j < 4; j++) acc[i][j] = (f32x4)0.f;

    const float* ap = A + (size_t)(bm + srow) * D_MODEL + scol;
    const unsigned short* whp = Wh + (size_t)(bn + srow) * D_MODEL + scol;
    const unsigned short* wlp = (split ? Wl : Wh) + (size_t)(bn + srow) * D_MODEL + scol;

    for (int k0 = 0; k0 < D_MODEL; k0 += 64) {
        alignas(16) float fl[32];
        #pragma unroll
        for (int c = 0; c < 8; c++) *(float4*)&fl[4 * c] = *(const float4*)(ap + 4 * c);
        uint4 w0 = *(const uint4*)(whp + 0),  w1 = *(const uint4*)(whp + 8);
        uint4 w2 = *(const uint4*)(whp + 16), w3 = *(const uint4*)(whp + 24);
        uint4 x0, x1, x2, x3;
        if (split) {
            x0 = *(const uint4*)(wlp + 0);  x1 = *(const uint4*)(wlp + 8);
            x2 = *(const uint4*)(wlp + 16); x3 = *(const uint4*)(wlp + 24);
        }
        ap += 64; whp += 64; wlp += 64;

        unsigned int hw[16], lw[16];
        #pragma unroll
        for (int c = 0; c < 16; c++) {
            unsigned short h0 = f2bf(fl[2 * c]), h1 = f2bf(fl[2 * c + 1]);
            hw[c] = (unsigned int)h0 | ((unsigned int)h1 << 16);
            if (split) {
                unsigned short l0 = f2bf(fl[2 * c] - bf2f(h0));
                unsigned short l1 = f2bf(fl[2 * c + 1] - bf2f(h1));
                lw[c] = (unsigned int)l0 | ((unsigned int)l1 << 16);
            }
        }

        __syncthreads();
        unsigned int* ah = (unsigned int*)&Ah[srow * GLDK + scol];
        #pragma unroll
        for (int g = 0; g < 4; g++)
            *(uint4*)(ah + 4 * g) = make_uint4(hw[4 * g], hw[4 * g + 1], hw[4 * g + 2], hw[4 * g + 3]);
        if (split) {
            unsigned int* al = (unsigned int*)&Al[srow * GLDK + scol];
            #pragma unroll
            for (int g = 0; g < 4; g++)
                *(uint4*)(al + 4 * g) = make_uint4(lw[4 * g], lw[4 * g + 1], lw[4 * g + 2], lw[4 * g + 3]);
        }
        unsigned short* ws = &Whs[srow * GLDK + scol];
        *(uint4*)(ws + 0) = w0; *(uint4*)(ws + 8)  = w1;
        *(uint4*)(ws + 16) = w2; *(uint4*)(ws + 24) = w3;
        if (split) {
            unsigned short* wl2 = &Wls[srow * GLDK + scol];
            *(uint4*)(wl2 + 0) = x0; *(uint4*)(wl2 + 8)  = x1;
            *(uint4*)(wl2 + 16) = x2; *(uint4*)(wl2 + 24) = x3;
        }
        __syncthreads();

        #pragma unroll
        for (int kc = 0; kc < 64; kc += 32) {
            bh8 ahf[4], whf[4];
            #pragma unroll
            for (int i = 0; i < 4; i++)
                ahf[i] = *(bh8*)&Ah[(wm + i * 16 + l15) * GLDK + kc + q4 * 8];
            #pragma unroll
            for (int j = 0; j < 4; j++)
                whf[j] = *(bh8*)&Whs[(wn + j * 16 + l15) * GLDK + kc + q4 * 8];
            #pragma unroll
            for (int i = 0; i < 4; i++)
                #pragma unroll
                for (int j = 0; j < 4; j++)
                    acc[i][j] = __builtin_amdgcn_mfma_f32_16x16x32_bf16(ahf[i], whf[j], acc[i][j], 0, 0, 0);
            if (split) {
                bh8 alf[4], wlf[4];
                #pragma unroll
                for (int i = 0; i < 4; i++)
                    alf[i] = *(bh8*)&Al[(wm + i * 16 + l15) * GLDK + kc + q4 * 8];
                #pragma unroll
                for (int j = 0; j < 4; j++)
                    wlf[j] = *(bh8*)&Wls[(wn + j * 16 + l15) * GLDK + kc + q4 * 8];
                #pragma unroll
                for (int i = 0; i < 4; i++)
                    #pragma unroll
                    for (int j = 0; j < 4; j++) {
                        acc[i][j] = __builtin_amdgcn_mfma_f32_16x16x32_bf16(ahf[i], wlf[j], acc[i][j], 0, 0, 0);
                        acc[i][j] = __builtin_amdgcn_mfma_f32_16x16x32_bf16(alf[i], whf[j], acc[i][j], 0, 0, 0);
                    }
            }
        }
    }

    #pragma unroll
    for (int j = 0; j < 4; j++) {
        int col = bn + wn + j * 16 + l15;
        int hh = col >> 6, dd = col & 63;
        float bv = Bi[col];
        #pragma unroll
        for (int i = 0; i < 4; i++) {
            int row0 = bm + wm + i * 16 + q4 * 4;
            int bb = row0 >> 10, tt = row0 & 1023;
            if (split) {
                float* yp = Yf + (((size_t)(bb * NHEAD + hh)) * T_SEQ + tt) * HDIM + dd;
                #pragma unroll
                for (int r = 0; r < 4; r++)
                    yp[(size_t)r * HDIM] = acc[i][j][r] + bv;
            } else {
                uint2 u;
                u.x = (unsigned int)f2bf(acc[i][j][0] + bv) | ((unsigned int)f2bf(acc[i][j][1] + bv) << 16);
                u.y = (unsigned int)f2bf(acc[i][j][2] + bv) | ((unsigned int)f2bf(acc[i][j][3] + bv) << 16);
                *(uint2*)(Yv + ((size_t)(bb * NHEAD + hh) * HDIM + dd) * T_SEQ + tt) = u;
            }
        }
    }
}

// ---------------------------------------------------------------------------
// Out-projection: bf16 ctx (model-major) @ bf16 W^T + bias, head mask on A.
// ---------------------------------------------------------------------------
__global__ __launch_bounds__(256, 2) void gemm_obf(
    const unsigned short* __restrict__ A, const unsigned short* __restrict__ W,
    const float* __restrict__ Bi, float* __restrict__ Y,
    const float* __restrict__ amask)
{
    __shared__ unsigned short As[128 * GLDK];
    __shared__ unsigned short Ws[128 * GLDK];

    int tid  = threadIdx.x;
    int bm   = blockIdx.y * 128, bn = blockIdx.x * 128;
    int wave = tid >> 6, lane = tid & 63;
    int l15  = lane & 15, q4 = lane >> 4;
    int wm   = (wave >> 1) * 64, wn = (wave & 1) * 64;
    int srow = tid >> 1;
    int scol = (tid & 1) * 32;
    int batch = bm >> 10;

    f32x4 acc[4][4];
    #pragma unroll
    for (int i = 0; i < 4; i++)
        #pragma unroll
        for (int j = 0; j < 4; j++) acc[i][j] = (f32x4)0.f;

    const unsigned short* ap = A + (size_t)(bm + srow) * D_MODEL + scol;
    const unsigned short* wp = W + (size_t)(bn + srow) * D_MODEL + scol;

    for (int k0 = 0; k0 < D_MODEL; k0 += 64) {
        uint4 a0 = *(const uint4*)(ap + 0),  a1 = *(const uint4*)(ap + 8);
        uint4 a2 = *(const uint4*)(ap + 16), a3 = *(const uint4*)(ap + 24);
        uint4 w0 = *(const uint4*)(wp + 0),  w1 = *(const uint4*)(wp + 8);
        uint4 w2 = *(const uint4*)(wp + 16), w3 = *(const uint4*)(wp + 24);
        ap += 64; wp += 64;
        if (amask[batch * NHEAD + (k0 >> 6)] == 0.f) {
            a0 = a1 = a2 = a3 = make_uint4(0, 0, 0, 0);
        }
        __syncthreads();
        unsigned short* as = &As[srow * GLDK + scol];
        *(uint4*)(as + 0) = a0; *(uint4*)(as + 8)  = a1;
        *(uint4*)(as + 16) = a2; *(uint4*)(as + 24) = a3;
        unsigned short* ws = &Ws[srow * GLDK + scol];
        *(uint4*)(ws + 0) = w0; *(uint4*)(ws + 8)  = w1;
        *(uint4*)(ws + 16) = w2; *(uint4*)(ws + 24) = w3;
        __syncthreads();

        #pragma unroll
        for (int kc = 0; kc < 64; kc += 32) {
            bh8 af[4], wf[4];
            #pragma unroll
            for (int i = 0; i < 4; i++)
                af[i] = *(bh8*)&As[(wm + i * 16 + l15) * GLDK + kc + q4 * 8];
            #pragma unroll
            for (int j = 0; j < 4; j++)
                wf[j] = *(bh8*)&Ws[(wn + j * 16 + l15) * GLDK + kc + q4 * 8];
            #pragma unroll
            for (int i = 0; i < 4; i++)
                #pragma unroll
                for (int j = 0; j < 4; j++)
                    acc[i][j] = __builtin_amdgcn_mfma_f32_16x16x32_bf16(af[i], wf[j], acc[i][j], 0, 0, 0);
        }
    }

    #pragma unroll
    for (int j = 0; j < 4; j++) {
        int col = bn + wn + j * 16 + l15;
        float bv = Bi[col];
        #pragma unroll
        for (int i = 0; i < 4; i++) {
            int row = bm + wm + i * 16 + q4 * 4;
            #pragma unroll
            for (int r = 0; r < 4; r++)
                Y[(size_t)(row + r) * D_MODEL + col] = acc[i][j][r] + bv;
        }
    }
}

// ---------------------------------------------------------------------------
// RMS-norm rows of 64 on HEAD-MAJOR fp32 arrays, in place.
// y==0: q (norm + top-k). y==1: k (norm only).
// ---------------------------------------------------------------------------
__global__ void normqk(float* __restrict__ Q, float* __restrict__ Kb)
{
    int tid  = threadIdx.x;
    int wid  = tid >> 6;
    int lane = tid & 63;
    long rid = (long)blockIdx.x * 4 + wid;   // [(b*16+h)*1024 + t]
    int isK  = blockIdx.y;
    int h    = (int)((rid >> 10) & 15);

    float* p = (isK ? Kb : Q) + rid * HDIM;
    float x = p[lane];
    float ss = x * x;
    #pragma unroll
    for (int off = 32; off > 0; off >>= 1) ss += __shfl_xor(ss, off);
    float rms = sqrtf(ss * (1.0f / 64.0f));
    float xn = x / (rms + 1e-6f);

    if (!isK) {
        float a = fabsf(xn);
        int cnt = 0;
        for (int j = 0; j < 64; j++) {
            float o = __shfl(a, j);
            cnt += (o > a) ? 1 : 0;
        }
        if (cnt >= KEEPC[h]) xn = 0.f;
    }
    p[lane] = xn;
}

// ---------------------------------------------------------------------------
// MFMA flash attention per (b,h,qt). Q,K fp32 head-major (split to bf16
// hi/lo on the fly -> fp32-quality logits); V^T bf16 [d][t]. P via LDS
// round-trip (C-layout -> A-layout). Vs overlays Kl after QK. Emits ctx
// bf16 (model-major) and sum(attn^2) per head (f64 atomics).
// ---------------------------------------------------------------------------
#define ATS 72   // LDS row stride in shorts (144 B, 16B-aligned rows)

__global__ __launch_bounds__(256, 3) void attn_kernel(
    const float* __restrict__ Qg, const float* __restrict__ Kg,
    const unsigned short* __restrict__ Vtg, unsigned short* __restrict__ Ctx,
    double* __restrict__ He)
{
    __shared__ unsigned short Qh[64 * ATS];
    __shared__ unsigned short Ql[64 * ATS];
    __shared__ unsigned short Kh[64 * ATS];
    __shared__ unsigned short KlV[64 * ATS];   // Kl during QK, then V^T tile
    __shared__ unsigned short Ps[64 * ATS];

    int tid = threadIdx.x;
    int qt = 15 - (int)blockIdx.x;     // heavy blocks first
    int h = blockIdx.y, b = blockIdx.z;
    size_t hoff = ((size_t)(b * NHEAD + h)) * T_SEQ * HDIM;

    int wave = tid >> 6, lane = tid & 63;
    int l15 = lane & 15, rg = lane >> 4;
    int st = tid >> 2, sd = (tid & 3) * 16;    // staging: row, 16-elem col

    {   // stage Q tile once, split hi/lo
        const float* qp = Qg + hoff + (size_t)(qt * 64 + st) * HDIM + sd;
        alignas(16) float f[16];
        #pragma unroll
        for (int c = 0; c < 4; c++) *(float4*)&f[4 * c] = *(const float4*)(qp + 4 * c);
        unsigned int hw[8], lw[8];
        #pragma unroll
        for (int c = 0; c < 8; c++) {
            unsigned short h0 = f2bf(f[2 * c]), h1 = f2bf(f[2 * c + 1]);
            hw[c] = (unsigned int)h0 | ((unsigned int)h1 << 16);
            unsigned short l0 = f2bf(f[2 * c] - bf2f(h0));
            unsigned short l1 = f2bf(f[2 * c + 1] - bf2f(h1));
            lw[c] = (unsigned int)l0 | ((unsigned int)l1 << 16);
        }
        unsigned int* dsth = (unsigned int*)&Qh[st * ATS + sd];
        unsigned int* dstl = (unsigned int*)&Ql[st * ATS + sd];
        *(uint4*)(dsth)     = make_uint4(hw[0], hw[1], hw[2], hw[3]);
        *(uint4*)(dsth + 4) = make_uint4(hw[4], hw[5], hw[6], hw[7]);
        *(uint4*)(dstl)     = make_uint4(lw[0], lw[1], lw[2], lw[3]);
        *(uint4*)(dstl + 4) = make_uint4(lw[4], lw[5], lw[6], lw[7]);
    }

    float m[4], l[4], s2[4];
    #pragma unroll
    for (int e = 0; e < 4; e++) { m[e] = -1e30f; l[e] = 0.f; s2[e] = 0.f; }
    f32x4 o[4];
    #pragma unroll
    for (int n = 0; n < 4; n++) o[n] = (f32x4)0.f;

    for (int kt = 0; kt <= qt; ++kt) {
        __syncthreads();   // prior iteration's PV reads done
        uint4 vt0, vt1;
        {   // stage K (split), prefetch V^T tile into regs
            const float* kp = Kg + hoff + (size_t)(kt * 64 + st) * HDIM + sd;
            alignas(16) float f[16];
            #pragma unroll
            for (int c = 0; c < 4; c++) *(float4*)&f[4 * c] = *(const float4*)(kp + 4 * c);
            const unsigned short* vp = Vtg + ((size_t)(b * NHEAD + h) * HDIM + st) * T_SEQ + kt * 64 + sd;
            vt0 = *(const uint4*)(vp);
            vt1 = *(const uint4*)(vp + 8);
            unsigned int hw[8], lw[8];
            #pragma unroll
            for (int c = 0; c < 8; c++) {
                unsigned short h0 = f2bf(f[2 * c]), h1 = f2bf(f[2 * c + 1]);
                hw[c] = (unsigned int)h0 | ((unsigned int)h1 << 16);
                unsigned short l0 = f2bf(f[2 * c] - bf2f(h0));
                unsigned short l1 = f2bf(f[2 * c + 1] - bf2f(h1));
                lw[c] = (unsigned int)l0 | ((unsigned int)l1 << 16);
            }
            unsigned int* dsth = (unsigned int*)&Kh[st * ATS + sd];
            unsigned int* dstl = (unsigned int*)&KlV[st * ATS + sd];
            *(uint4*)(dsth)     = make_uint4(hw[0], hw[1], hw[2], hw[3]);
            *(uint4*)(dsth + 4) = make_uint4(hw[4], hw[5], hw[6], hw[7]);
            *(uint4*)(dstl)     = make_uint4(lw[0], lw[1], lw[2], lw[3]);
            *(uint4*)(dstl + 4) = make_uint4(lw[4], lw[5], lw[6], lw[7]);
        }
        __syncthreads();

        // ---- QK^T (split-bf16, 3 passes) -> S rows wave*16.., cols 0..63
        f32x4 s[4];
        #pragma unroll
        for (int n = 0; n < 4; n++) s[n] = (f32x4)0.f;
        #pragma unroll
        for (int kc = 0; kc < 64; kc += 32) {
            bh8 qa = *(bh8*)&Qh[(wave * 16 + l15) * ATS + kc + rg * 8];
            bh8 ql = *(bh8*)&Ql[(wave * 16 + l15) * ATS + kc + rg * 8];
            #pragma unroll
            for (int n = 0; n < 4; n++) {
                bh8 ka = *(bh8*)&Kh[(n * 16 + l15) * ATS + kc + rg * 8];
                bh8 kl = *(bh8*)&KlV[(n * 16 + l15) * ATS + kc + rg * 8];
                s[n] = __builtin_amdgcn_mfma_f32_16x16x32_bf16(qa, ka, s[n], 0, 0, 0);
                s[n] = __builtin_amdgcn_mfma_f32_16x16x32_bf16(qa, kl, s[n], 0, 0, 0);
                s[n] = __builtin_amdgcn_mfma_f32_16x16x32_bf16(ql, ka, s[n], 0, 0, 0);
            }
        }

        if (kt == qt) {   // causal mask within diagonal tile
            #pragma unroll
            for (int n = 0; n < 4; n++)
                #pragma unroll
                for (int e = 0; e < 4; e++)
                    if (n * 16 + l15 > wave * 16 + rg * 4 + e) s[n][e] = -1e30f;
        }

        // ---- online softmax (C-layout rows rg*4+e; reduce over l15 lanes)
        float al[4];
        #pragma unroll
        for (int e = 0; e < 4; e++) {
            float mx = fmaxf(fmaxf(s[0][e], s[1][e]), fmaxf(s[2][e], s[3][e]));
            #pragma unroll
            for (int off = 1; off < 16; off <<= 1) mx = fmaxf(mx, __shfl_xor(mx, off));
            float mn = fmaxf(m[e], mx);
            al[e] = __expf(m[e] - mn);
            m[e] = mn;
            float rs = 0.f, rs2 = 0.f;
            #pragma unroll
            for (int n = 0; n < 4; n++) {
                float pv = __expf(s[n][e] - mn);
                s[n][e] = pv;
                rs += pv; rs2 += pv * pv;
            }
            #pragma unroll
            for (int off = 1; off < 16; off <<= 1) {
                rs  += __shfl_xor(rs, off);
                rs2 += __shfl_xor(rs2, off);
            }
            l[e]  = l[e] * al[e] + rs;
            s2[e] = s2[e] * al[e] * al[e] + rs2;
        }

        __syncthreads();   // all QK reads of KlV done
        {   // V^T tile into KlV space; P (bf16) into Ps
            unsigned short* dv = &KlV[st * ATS + sd];
            *(uint4*)(dv)     = vt0;
            *(uint4*)(dv + 8) = vt1;
            #pragma unroll
            for (int n = 0; n < 4; n++)
                #pragma unroll
                for (int e = 0; e < 4; e++)
                    Ps[(wave * 16 + rg * 4 + e) * ATS + n * 16 + l15] = f2bf(s[n][e]);
        }
        __syncthreads();   // Vs visible to all waves (Ps is intra-wave)

        // ---- rescale O, then P @ V
        #pragma unroll
        for (int n = 0; n < 4; n++)
            #pragma unroll
            for (int e = 0; e < 4; e++) o[n][e] *= al[e];

        #pragma unroll
        for (int kc = 0; kc < 64; kc += 32) {
            bh8 pa = *(bh8*)&Ps[(wave * 16 + l15) * ATS + kc + rg * 8];
            #pragma unroll
            for (int n = 0; n < 4; n++) {
                bh8 vb = *(bh8*)&KlV[(n * 16 + l15) * ATS + kc + rg * 8];
                o[n] = __builtin_amdgcn_mfma_f32_16x16x32_bf16(pa, vb, o[n], 0, 0, 0);
            }
        }
    }

    float linv[4];
    #pragma unroll
    for (int e = 0; e < 4; e++) linv[e] = 1.f / l[e];

    float en = 0.f;
    #pragma unroll
    for (int e = 0; e < 4; e++) en += s2[e] * linv[e] * linv[e];
    en += __shfl_xor(en, 16);
    en += __shfl_xor(en, 32);
    if (lane == 0) atomicAdd(&He[b * NHEAD + h], (double)en);

    #pragma unroll
    for (int n = 0; n < 4; n++)
        #pragma unroll
        for (int e = 0; e < 4; e++) {
            int row = qt * 64 + wave * 16 + rg * 4 + e;
            Ctx[((size_t)b * T_SEQ + row) * D_MODEL + h * HDIM + n * 16 + l15] =
                f2bf(o[n][e] * linv[e]);
        }
}

// ---------------------------------------------------------------------------
// Per-batch head selection (unchanged).
// ---------------------------------------------------------------------------
__global__ void headsel(const double* __restrict__ He, float* __restrict__ Mask)
{
    int b = threadIdx.x;
    if (b >= BATCH) return;
    double e[NHEAD];
    double mx = -1e300;
    for (int h = 0; h < NHEAD; h++) {
        e[h] = He[b * NHEAD + h] / (1024.0 * 1024.0);
        mx = fmax(mx, e[h]);
    }
    double p[NHEAD], s = 0.0;
    for (int h = 0; h < NHEAD; h++) { p[h] = exp(e[h] - mx); s += p[h]; }
    double ent = 0.0;
    for (int h = 0; h < NHEAD; h++) {
        double ph = p[h] / s;
        ent -= ph * log(ph + 1e-9);
    }
    double entn = ent / log(16.0);
    entn = fmin(fmax(entn, 0.0), 1.0);
    int keep = (int)rint(2.0 + entn * 4.0);
    if (keep < 1) keep = 1;
    if (keep > NHEAD) keep = NHEAD;
    double srt[NHEAD];
    for (int h = 0; h < NHEAD; h++) srt[h] = e[h];
    for (int i = 1; i < NHEAD; i++) {
        double v = srt[i]; int j = i - 1;
        while (j >= 0 && srt[j] < v) { srt[j + 1] = srt[j]; j--; }
        srt[j + 1] = v;
    }
    double th = srt[keep - 1];
    for (int h = 0; h < NHEAD; h++)
        Mask[b * NHEAD + h] = (e[h] >= th) ? 1.0f : 0.0f;
}

// ---------------------------------------------------------------------------
extern "C" void kernel_launch(void* const* d_in, const int* in_sizes, int n_in,
                              void* d_out, int out_size, void* d_ws, size_t ws_size,
                              hipStream_t stream)
{
    (void)in_sizes; (void)n_in; (void)out_size; (void)ws_size;
    const float* x  = (const float*)d_in[0];
    const float* qw = (const float*)d_in[1];
    const float* qb = (const float*)d_in[2];
    const float* kw = (const float*)d_in[3];
    const float* kb = (const float*)d_in[4];
    const float* vw = (const float*)d_in[5];
    const float* vb = (const float*)d_in[6];
    const float* ow = (const float*)d_in[7];
    const float* ob = (const float*)d_in[8];
    float* out = (float*)d_out;

    char* base = (char*)d_ws;
    const size_t MB = (size_t)1024 * 1024;
    float*          q_hm = (float*)(base);                   // 16 MB head-major
    float*          k_hm = (float*)(base + 16 * MB);         // 16 MB head-major
    unsigned short* vt   = (unsigned short*)(base + 32 * MB); // 8 MB V^T bf16
    unsigned short* ctxb = (unsigned short*)(base + 40 * MB); // 8 MB bf16
    unsigned short* kwh  = (unsigned short*)(base + 48 * MB); // 2 MB
    unsigned short* kwl  = (unsigned short*)(base + 50 * MB);
    unsigned short* vwb  = (unsigned short*)(base + 52 * MB);
    unsigned short* owb  = (unsigned short*)(base + 54 * MB);
    double*         he   = (double*)(base + 56 * MB);
    float*          mask = (float*)(base + 56 * MB + 512);

    hipMemsetAsync(he, 0, 64 * sizeof(double), stream);

    cast_weights<<<1536, 256, 0, stream>>>(kw, kwh, kwl, vw, vwb, ow, owb);
    // q projection: f64 accumulation, head-major out
    gemm_sign_f64<<<dim3(16, 64), 256, 0, stream>>>(x, qw, qb, q_hm);
    // k projection: split-bf16 MFMA, fp32 head-major out
    gemm_xsplit<<<dim3(8, 32), 256, 0, stream>>>(x, kwh, kwl, kb, k_hm, nullptr, 1);
    // v projection: bf16 MFMA, V^T bf16 out
    gemm_xsplit<<<dim3(8, 32), 256, 0, stream>>>(x, vwb, nullptr, vb, nullptr, vt, 0);
    normqk<<<dim3(16384, 2), 256, 0, stream>>>(q_hm, k_hm);
    attn_kernel<<<dim3(16, 16, 4), 256, 0, stream>>>(q_hm, k_hm, vt, ctxb, he);
    headsel<<<1, 64, 0, stream>>>(he, mask);
    gemm_obf<<<dim3(8, 32), 256, 0, stream>>>(ctxb, owb, ob, out, mask);
}

// Round 5
// 467.564 us; speedup vs baseline: 2.1040x; 1.1872x over previous
//
#include <hip/hip_runtime.h>
#include <math.h>

#define D_MODEL 1024
#define T_SEQ   1024
#define BATCH   4
#define NHEAD   16
#define HDIM    64

// keep counts: trunc(linspace(0.35,0.15,16)*64), min 1
__constant__ int KEEPC[16] = {22,21,20,19,18,18,17,16,15,14,13,13,12,11,10,9};

typedef short bh8  __attribute__((ext_vector_type(8)));
typedef float f32x4 __attribute__((ext_vector_type(4)));
typedef int   i32x4 __attribute__((ext_vector_type(4)));

__device__ __forceinline__ unsigned short f2bf(float f) {
    unsigned int u = __float_as_uint(f);
    return (unsigned short)((u + 0x7FFFu + ((u >> 16) & 1u)) >> 16);
}
__device__ __forceinline__ float bf2f(unsigned short h) {
    return __uint_as_float(((unsigned int)h) << 16);
}

// ---------------------------------------------------------------------------
// Cast weights once: kw -> (hi,lo) bf16 split; vw, ow -> single bf16.
// ---------------------------------------------------------------------------
__global__ void cast_weights(const float* __restrict__ kw,
                             unsigned short* __restrict__ kwh,
                             unsigned short* __restrict__ kwl,
                             const float* __restrict__ vw,
                             unsigned short* __restrict__ vwb,
                             const float* __restrict__ ow,
                             unsigned short* __restrict__ owb)
{
    const int NS = (D_MODEL * D_MODEL) / 8;
    int i = blockIdx.x * 256 + threadIdx.x;
    const float* src; unsigned short* dh; unsigned short* dl = nullptr;
    long off;
    if (i < NS)           { src = kw; dh = kwh; dl = kwl; off = i; }
    else if (i < 2 * NS)  { src = vw; dh = vwb; off = i - NS; }
    else if (i < 3 * NS)  { src = ow; dh = owb; off = i - 2 * NS; }
    else return;
    long e = off * 8;
    alignas(16) float fl[8];
    *(float4*)&fl[0] = *(const float4*)(src + e);
    *(float4*)&fl[4] = *(const float4*)(src + e + 4);
    uint4 hp, lp;
    unsigned int* hpw = (unsigned int*)&hp;
    unsigned int* lpw = (unsigned int*)&lp;
    #pragma unroll
    for (int c = 0; c < 4; c++) {
        unsigned short h0 = f2bf(fl[2 * c]), h1 = f2bf(fl[2 * c + 1]);
        hpw[c] = (unsigned int)h0 | ((unsigned int)h1 << 16);
        if (dl) {
            unsigned short l0 = f2bf(fl[2 * c] - bf2f(h0));
            unsigned short l1 = f2bf(fl[2 * c + 1] - bf2f(h1));
            lpw[c] = (unsigned int)l0 | ((unsigned int)l1 << 16);
        }
    }
    *(uint4*)(dh + e) = hp;
    if (dl) *(uint4*)(dl + e) = lp;
}

// ---------------------------------------------------------------------------
// prep_q: x -> 4 signed base-256 digit planes of n = rint(x * 2^23)
// (exact: n = d0 + 256 d1 + 65536 d2 + 16777216 d3, |n| < 2^26), and
// qw -> sign int8. Quantization noise per q-row ~1.1e-6 << order-stat gap.
// ---------------------------------------------------------------------------
__global__ void prep_q(const float* __restrict__ x, signed char* __restrict__ dig,
                       const float* __restrict__ qw, signed char* __restrict__ sg)
{
    const int NX = (BATCH * T_SEQ * D_MODEL) / 8;   // 524288
    const int NW = (D_MODEL * D_MODEL) / 8;         // 131072
    const long PL = (long)BATCH * T_SEQ * D_MODEL;  // plane stride 4194304
    int i = blockIdx.x * 256 + threadIdx.x;
    if (i < NX) {
        long e = (long)i * 8;
        alignas(16) float f[8];
        *(float4*)&f[0] = *(const float4*)(x + e);
        *(float4*)&f[4] = *(const float4*)(x + e + 4);
        signed char d[4][8];
        #pragma unroll
        for (int c = 0; c < 8; c++) {
            int n = (int)rintf(f[c] * 8388608.0f);
            int d0 = (signed char)(n & 0xff); n = (n - d0) >> 8;
            int d1 = (signed char)(n & 0xff); n = (n - d1) >> 8;
            int d2 = (signed char)(n & 0xff); n = (n - d2) >> 8;
            d[0][c] = (signed char)d0; d[1][c] = (signed char)d1;
            d[2][c] = (signed char)d2; d[3][c] = (signed char)n;
        }
        #pragma unroll
        for (int p = 0; p < 4; p++)
            *(uint2*)(dig + p * PL + e) = *(uint2*)&d[p][0];
    } else if (i < NX + NW) {
        long e = (long)(i - NX) * 8;
        alignas(16) float f[8];
        *(float4*)&f[0] = *(const float4*)(qw + e);
        *(float4*)&f[4] = *(const float4*)(qw + e + 4);
        signed char s[8];
        #pragma unroll
        for (int c = 0; c < 8; c++)
            s[c] = (signed char)((f[c] > 0.f) - (f[c] < 0.f));
        *(uint2*)(sg + e) = *(uint2*)&s[0];
    }
}

// ---------------------------------------------------------------------------
// Q projection via EXACT int8 MFMA: q = 2^-23 * sum_p 256^p (Dp @ S^T) + b.
// i32 accumulators are exact (|acc| <= 1024*128); digits combined in i64.
// 64x64 block, 4 waves (2x2) each 32x32 via 2x2 of mfma_i32_16x16x64_i8.
// Output fp32 HEAD-MAJOR: [(b*16+h)*1024 + t][d].
// ---------------------------------------------------------------------------
#define QST 80   // LDS row stride bytes (16B-aligned; worst 2-way bank alias)

__global__ __launch_bounds__(256, 2) void gemm_q_i8(
    const signed char* __restrict__ dig, const signed char* __restrict__ sg,
    const float* __restrict__ Bi, float* __restrict__ Y)
{
    __shared__ signed char Ad[4][64 * QST];
    __shared__ signed char Bs[64 * QST];

    const long PL = (long)BATCH * T_SEQ * D_MODEL;
    int tid  = threadIdx.x;
    int bm   = blockIdx.y * 64, bn = blockIdx.x * 64;
    int wave = tid >> 6, lane = tid & 63;
    int l15  = lane & 15, rg = lane >> 4;
    int wm   = (wave >> 1) * 32, wn = (wave & 1) * 32;
    int srow = tid >> 2;            // 0..63
    int skof = (tid & 3) * 16;      // 0,16,32,48

    i32x4 acc[4][2][2];
    #pragma unroll
    for (int p = 0; p < 4; p++)
        #pragma unroll
        for (int i = 0; i < 2; i++)
            #pragma unroll
            for (int j = 0; j < 2; j++) acc[p][i][j] = (i32x4)0;

    const signed char* ap = dig + (size_t)(bm + srow) * D_MODEL + skof;
    const signed char* bp = sg + (size_t)(bn + srow) * D_MODEL + skof;

    for (int k0 = 0; k0 < D_MODEL; k0 += 64) {
        uint4 av[4], bv;
        #pragma unroll
        for (int p = 0; p < 4; p++) av[p] = *(const uint4*)(ap + p * PL);
        bv = *(const uint4*)(bp);
        ap += 64; bp += 64;

        __syncthreads();
        #pragma unroll
        for (int p = 0; p < 4; p++)
            *(uint4*)&Ad[p][srow * QST + skof] = av[p];
        *(uint4*)&Bs[srow * QST + skof] = bv;
        __syncthreads();

        i32x4 bf[2];
        #pragma unroll
        for (int j = 0; j < 2; j++)
            bf[j] = *(i32x4*)&Bs[(wn + j * 16 + l15) * QST + rg * 16];
        #pragma unroll
        for (int p = 0; p < 4; p++) {
            i32x4 af[2];
            #pragma unroll
            for (int i = 0; i < 2; i++)
                af[i] = *(i32x4*)&Ad[p][(wm + i * 16 + l15) * QST + rg * 16];
            #pragma unroll
            for (int i = 0; i < 2; i++)
                #pragma unroll
                for (int j = 0; j < 2; j++)
                    acc[p][i][j] = __builtin_amdgcn_mfma_i32_16x16x64_i8(
                        af[i], bf[j], acc[p][i][j], 0, 0, 0);
        }
    }

    // epilogue: exact i64 digit combine, scale 2^-23, bias, head-major store
    int hh = bn >> 6;   // N-block spans exactly one head
    #pragma unroll
    for (int j = 0; j < 2; j++) {
        int col = bn + wn + j * 16 + l15;
        int dd = col & 63;
        float bvv = Bi[col];
        #pragma unroll
        for (int i = 0; i < 2; i++) {
            #pragma unroll
            for (int r = 0; r < 4; r++) {
                int row = bm + wm + i * 16 + rg * 4 + r;
                int bb = row >> 10, tt = row & 1023;
                long t = (long)acc[0][i][j][r]
                       + ((long)acc[1][i][j][r] << 8)
                       + ((long)acc[2][i][j][r] << 16)
                       + ((long)acc[3][i][j][r] << 24);
                float o = (float)((double)t * (1.0 / 8388608.0)) + bvv;
                Y[(((size_t)(bb * NHEAD + hh)) * T_SEQ + tt) * HDIM + dd] = o;
            }
        }
    }
}

// ---------------------------------------------------------------------------
// MFMA GEMM, bf16 split of fp32 A on the fly.
// split=1 (k-proj): 3-pass hi/lo product, fp32 out HEAD-MAJOR into Yf.
// split=0 (v-proj): single bf16 pass, bf16 out TRANSPOSED head-major
//                   Yv[(b*16+h)*64 + d][t]  (V^T for attention B-operand).
// ---------------------------------------------------------------------------
#define GLDK 72

__global__ __launch_bounds__(256, 2) void gemm_xsplit(
    const float* __restrict__ A, const unsigned short* __restrict__ Wh,
    const unsigned short* __restrict__ Wl, const float* __restrict__ Bi,
    float* __restrict__ Yf, unsigned short* __restrict__ Yv, int split)
{
    __shared__ unsigned short Ah[128 * GLDK];
    __shared__ unsigned short Al[128 * GLDK];
    __shared__ unsigned short Whs[128 * GLDK];
    __shared__ unsigned short Wls[128 * GLDK];

    int tid  = threadIdx.x;
    int bm   = blockIdx.y * 128, bn = blockIdx.x * 128;
    int wave = tid >> 6, lane = tid & 63;
    int l15  = lane & 15, q4 = lane >> 4;
    int wm   = (wave >> 1) * 64, wn = (wave & 1) * 64;
    int srow = tid >> 1;
    int scol = (tid & 1) * 32;

    f32x4 acc[4][4];
    #pragma unroll
    for (int i = 0; i < 4; i++)
        #pragma unroll
        for (int j = 0; j < 4; j++) acc[i][j] = (f32x4)0.f;

    const float* ap = A + (size_t)(bm + srow) * D_MODEL + scol;
    const unsigned short* whp = Wh + (size_t)(bn + srow) * D_MODEL + scol;
    const unsigned short* wlp = (split ? Wl : Wh) + (size_t)(bn + srow) * D_MODEL + scol;

    for (int k0 = 0; k0 < D_MODEL; k0 += 64) {
        alignas(16) float fl[32];
        #pragma unroll
        for (int c = 0; c < 8; c++) *(float4*)&fl[4 * c] = *(const float4*)(ap + 4 * c);
        uint4 w0 = *(const uint4*)(whp + 0),  w1 = *(const uint4*)(whp + 8);
        uint4 w2 = *(const uint4*)(whp + 16), w3 = *(const uint4*)(whp + 24);
        uint4 x0, x1, x2, x3;
        if (split) {
            x0 = *(const uint4*)(wlp + 0);  x1 = *(const uint4*)(wlp + 8);
            x2 = *(const uint4*)(wlp + 16); x3 = *(const uint4*)(wlp + 24);
        }
        ap += 64; whp += 64; wlp += 64;

        unsigned int hw[16], lw[16];
        #pragma unroll
        for (int c = 0; c < 16; c++) {
            unsigned short h0 = f2bf(fl[2 * c]), h1 = f2bf(fl[2 * c + 1]);
            hw[c] = (unsigned int)h0 | ((unsigned int)h1 << 16);
            if (split) {
                unsigned short l0 = f2bf(fl[2 * c] - bf2f(h0));
                unsigned short l1 = f2bf(fl[2 * c + 1] - bf2f(h1));
                lw[c] = (unsigned int)l0 | ((unsigned int)l1 << 16);
            }
        }

        __syncthreads();
        unsigned int* ah = (unsigned int*)&Ah[srow * GLDK + scol];
        #pragma unroll
        for (int g = 0; g < 4; g++)
            *(uint4*)(ah + 4 * g) = make_uint4(hw[4 * g], hw[4 * g + 1], hw[4 * g + 2], hw[4 * g + 3]);
        if (split) {
            unsigned int* al = (unsigned int*)&Al[srow * GLDK + scol];
            #pragma unroll
            for (int g = 0; g < 4; g++)
                *(uint4*)(al + 4 * g) = make_uint4(lw[4 * g], lw[4 * g + 1], lw[4 * g + 2], lw[4 * g + 3]);
        }
        unsigned short* ws = &Whs[srow * GLDK + scol];
        *(uint4*)(ws + 0) = w0; *(uint4*)(ws + 8)  = w1;
        *(uint4*)(ws + 16) = w2; *(uint4*)(ws + 24) = w3;
        if (split) {
            unsigned short* wl2 = &Wls[srow * GLDK + scol];
            *(uint4*)(wl2 + 0) = x0; *(uint4*)(wl2 + 8)  = x1;
            *(uint4*)(wl2 + 16) = x2; *(uint4*)(wl2 + 24) = x3;
        }
        __syncthreads();

        #pragma unroll
        for (int kc = 0; kc < 64; kc += 32) {
            bh8 ahf[4], whf[4];
            #pragma unroll
            for (int i = 0; i < 4; i++)
                ahf[i] = *(bh8*)&Ah[(wm + i * 16 + l15) * GLDK + kc + q4 * 8];
            #pragma unroll
            for (int j = 0; j < 4; j++)
                whf[j] = *(bh8*)&Whs[(wn + j * 16 + l15) * GLDK + kc + q4 * 8];
            #pragma unroll
            for (int i = 0; i < 4; i++)
                #pragma unroll
                for (int j = 0; j < 4; j++)
                    acc[i][j] = __builtin_amdgcn_mfma_f32_16x16x32_bf16(ahf[i], whf[j], acc[i][j], 0, 0, 0);
            if (split) {
                bh8 alf[4], wlf[4];
                #pragma unroll
                for (int i = 0; i < 4; i++)
                    alf[i] = *(bh8*)&Al[(wm + i * 16 + l15) * GLDK + kc + q4 * 8];
                #pragma unroll
                for (int j = 0; j < 4; j++)
                    wlf[j] = *(bh8*)&Wls[(wn + j * 16 + l15) * GLDK + kc + q4 * 8];
                #pragma unroll
                for (int i = 0; i < 4; i++)
                    #pragma unroll
                    for (int j = 0; j < 4; j++) {
                        acc[i][j] = __builtin_amdgcn_mfma_f32_16x16x32_bf16(ahf[i], wlf[j], acc[i][j], 0, 0, 0);
                        acc[i][j] = __builtin_amdgcn_mfma_f32_16x16x32_bf16(alf[i], whf[j], acc[i][j], 0, 0, 0);
                    }
            }
        }
    }

    #pragma unroll
    for (int j = 0; j < 4; j++) {
        int col = bn + wn + j * 16 + l15;
        int hh = col >> 6, dd = col & 63;
        float bv = Bi[col];
        #pragma unroll
        for (int i = 0; i < 4; i++) {
            int row0 = bm + wm + i * 16 + q4 * 4;
            int bb = row0 >> 10, tt = row0 & 1023;
            if (split) {
                float* yp = Yf + (((size_t)(bb * NHEAD + hh)) * T_SEQ + tt) * HDIM + dd;
                #pragma unroll
                for (int r = 0; r < 4; r++)
                    yp[(size_t)r * HDIM] = acc[i][j][r] + bv;
            } else {
                uint2 u;
                u.x = (unsigned int)f2bf(acc[i][j][0] + bv) | ((unsigned int)f2bf(acc[i][j][1] + bv) << 16);
                u.y = (unsigned int)f2bf(acc[i][j][2] + bv) | ((unsigned int)f2bf(acc[i][j][3] + bv) << 16);
                *(uint2*)(Yv + ((size_t)(bb * NHEAD + hh) * HDIM + dd) * T_SEQ + tt) = u;
            }
        }
    }
}

// ---------------------------------------------------------------------------
// Out-projection: bf16 ctx (model-major) @ bf16 W^T + bias, head mask on A.
// ---------------------------------------------------------------------------
__global__ __launch_bounds__(256, 2) void gemm_obf(
    const unsigned short* __restrict__ A, const unsigned short* __restrict__ W,
    const float* __restrict__ Bi, float* __restrict__ Y,
    const float* __restrict__ amask)
{
    __shared__ unsigned short As[128 * GLDK];
    __shared__ unsigned short Ws[128 * GLDK];

    int tid  = threadIdx.x;
    int bm   = blockIdx.y * 128, bn = blockIdx.x * 128;
    int wave = tid >> 6, lane = tid & 63;
    int l15  = lane & 15, q4 = lane >> 4;
    int wm   = (wave >> 1) * 64, wn = (wave & 1) * 64;
    int srow = tid >> 1;
    int scol = (tid & 1) * 32;
    int batch = bm >> 10;

    f32x4 acc[4][4];
    #pragma unroll
    for (int i = 0; i < 4; i++)
        #pragma unroll
        for (int j = 0; j < 4; j++) acc[i][j] = (f32x4)0.f;

    const unsigned short* ap = A + (size_t)(bm + srow) * D_MODEL + scol;
    const unsigned short* wp = W + (size_t)(bn + srow) * D_MODEL + scol;

    for (int k0 = 0; k0 < D_MODEL; k0 += 64) {
        uint4 a0 = *(const uint4*)(ap + 0),  a1 = *(const uint4*)(ap + 8);
        uint4 a2 = *(const uint4*)(ap + 16), a3 = *(const uint4*)(ap + 24);
        uint4 w0 = *(const uint4*)(wp + 0),  w1 = *(const uint4*)(wp + 8);
        uint4 w2 = *(const uint4*)(wp + 16), w3 = *(const uint4*)(wp + 24);
        ap += 64; wp += 64;
        if (amask[batch * NHEAD + (k0 >> 6)] == 0.f) {
            a0 = a1 = a2 = a3 = make_uint4(0, 0, 0, 0);
        }
        __syncthreads();
        unsigned short* as = &As[srow * GLDK + scol];
        *(uint4*)(as + 0) = a0; *(uint4*)(as + 8)  = a1;
        *(uint4*)(as + 16) = a2; *(uint4*)(as + 24) = a3;
        unsigned short* ws = &Ws[srow * GLDK + scol];
        *(uint4*)(ws + 0) = w0; *(uint4*)(ws + 8)  = w1;
        *(uint4*)(ws + 16) = w2; *(uint4*)(ws + 24) = w3;
        __syncthreads();

        #pragma unroll
        for (int kc = 0; kc < 64; kc += 32) {
            bh8 af[4], wf[4];
            #pragma unroll
            for (int i = 0; i < 4; i++)
                af[i] = *(bh8*)&As[(wm + i * 16 + l15) * GLDK + kc + q4 * 8];
            #pragma unroll
            for (int j = 0; j < 4; j++)
                wf[j] = *(bh8*)&Ws[(wn + j * 16 + l15) * GLDK + kc + q4 * 8];
            #pragma unroll
            for (int i = 0; i < 4; i++)
                #pragma unroll
                for (int j = 0; j < 4; j++)
                    acc[i][j] = __builtin_amdgcn_mfma_f32_16x16x32_bf16(af[i], wf[j], acc[i][j], 0, 0, 0);
        }
    }

    #pragma unroll
    for (int j = 0; j < 4; j++) {
        int col = bn + wn + j * 16 + l15;
        float bv = Bi[col];
        #pragma unroll
        for (int i = 0; i < 4; i++) {
            int row = bm + wm + i * 16 + q4 * 4;
            #pragma unroll
            for (int r = 0; r < 4; r++)
                Y[(size_t)(row + r) * D_MODEL + col] = acc[i][j][r] + bv;
        }
    }
}

// ---------------------------------------------------------------------------
// RMS-norm rows of 64 on HEAD-MAJOR fp32 arrays, in place.
// y==0: q (norm + top-k). y==1: k (norm only).
// ---------------------------------------------------------------------------
__global__ void normqk(float* __restrict__ Q, float* __restrict__ Kb)
{
    int tid  = threadIdx.x;
    int wid  = tid >> 6;
    int lane = tid & 63;
    long rid = (long)blockIdx.x * 4 + wid;   // [(b*16+h)*1024 + t]
    int isK  = blockIdx.y;
    int h    = (int)((rid >> 10) & 15);

    float* p = (isK ? Kb : Q) + rid * HDIM;
    float x = p[lane];
    float ss = x * x;
    #pragma unroll
    for (int off = 32; off > 0; off >>= 1) ss += __shfl_xor(ss, off);
    float rms = sqrtf(ss * (1.0f / 64.0f));
    float xn = x / (rms + 1e-6f);

    if (!isK) {
        float a = fabsf(xn);
        int cnt = 0;
        for (int j = 0; j < 64; j++) {
            float o = __shfl(a, j);
            cnt += (o > a) ? 1 : 0;
        }
        if (cnt >= KEEPC[h]) xn = 0.f;
    }
    p[lane] = xn;
}

// ---------------------------------------------------------------------------
// MFMA flash attention per (b,h,qt). Q,K fp32 head-major (split to bf16
// hi/lo on the fly -> fp32-quality logits); V^T bf16 [d][t]. P via LDS
// round-trip (C-layout -> A-layout). Vs overlays Kl after QK. Emits ctx
// bf16 (model-major) and sum(attn^2) per head (f64 atomics).
// ---------------------------------------------------------------------------
#define ATS 72   // LDS row stride in shorts (144 B, 16B-aligned rows)

__global__ __launch_bounds__(256, 3) void attn_kernel(
    const float* __restrict__ Qg, const float* __restrict__ Kg,
    const unsigned short* __restrict__ Vtg, unsigned short* __restrict__ Ctx,
    double* __restrict__ He)
{
    __shared__ unsigned short Qh[64 * ATS];
    __shared__ unsigned short Ql[64 * ATS];
    __shared__ unsigned short Kh[64 * ATS];
    __shared__ unsigned short KlV[64 * ATS];   // Kl during QK, then V^T tile
    __shared__ unsigned short Ps[64 * ATS];

    int tid = threadIdx.x;
    int qt = 15 - (int)blockIdx.x;     // heavy blocks first
    int h = blockIdx.y, b = blockIdx.z;
    size_t hoff = ((size_t)(b * NHEAD + h)) * T_SEQ * HDIM;

    int wave = tid >> 6, lane = tid & 63;
    int l15 = lane & 15, rg = lane >> 4;
    int st = tid >> 2, sd = (tid & 3) * 16;    // staging: row, 16-elem col

    {   // stage Q tile once, split hi/lo
        const float* qp = Qg + hoff + (size_t)(qt * 64 + st) * HDIM + sd;
        alignas(16) float f[16];
        #pragma unroll
        for (int c = 0; c < 4; c++) *(float4*)&f[4 * c] = *(const float4*)(qp + 4 * c);
        unsigned int hw[8], lw[8];
        #pragma unroll
        for (int c = 0; c < 8; c++) {
            unsigned short h0 = f2bf(f[2 * c]), h1 = f2bf(f[2 * c + 1]);
            hw[c] = (unsigned int)h0 | ((unsigned int)h1 << 16);
            unsigned short l0 = f2bf(f[2 * c] - bf2f(h0));
            unsigned short l1 = f2bf(f[2 * c + 1] - bf2f(h1));
            lw[c] = (unsigned int)l0 | ((unsigned int)l1 << 16);
        }
        unsigned int* dsth = (unsigned int*)&Qh[st * ATS + sd];
        unsigned int* dstl = (unsigned int*)&Ql[st * ATS + sd];
        *(uint4*)(dsth)     = make_uint4(hw[0], hw[1], hw[2], hw[3]);
        *(uint4*)(dsth + 4) = make_uint4(hw[4], hw[5], hw[6], hw[7]);
        *(uint4*)(dstl)     = make_uint4(lw[0], lw[1], lw[2], lw[3]);
        *(uint4*)(dstl + 4) = make_uint4(lw[4], lw[5], lw[6], lw[7]);
    }

    float m[4], l[4], s2[4];
    #pragma unroll
    for (int e = 0; e < 4; e++) { m[e] = -1e30f; l[e] = 0.f; s2[e] = 0.f; }
    f32x4 o[4];
    #pragma unroll
    for (int n = 0; n < 4; n++) o[n] = (f32x4)0.f;

    for (int kt = 0; kt <= qt; ++kt) {
        __syncthreads();   // prior iteration's PV reads done
        uint4 vt0, vt1;
        {   // stage K (split), prefetch V^T tile into regs
            const float* kp = Kg + hoff + (size_t)(kt * 64 + st) * HDIM + sd;
            alignas(16) float f[16];
            #pragma unroll
            for (int c = 0; c < 4; c++) *(float4*)&f[4 * c] = *(const float4*)(kp + 4 * c);
            const unsigned short* vp = Vtg + ((size_t)(b * NHEAD + h) * HDIM + st) * T_SEQ + kt * 64 + sd;
            vt0 = *(const uint4*)(vp);
            vt1 = *(const uint4*)(vp + 8);
            unsigned int hw[8], lw[8];
            #pragma unroll
            for (int c = 0; c < 8; c++) {
                unsigned short h0 = f2bf(f[2 * c]), h1 = f2bf(f[2 * c + 1]);
                hw[c] = (unsigned int)h0 | ((unsigned int)h1 << 16);
                unsigned short l0 = f2bf(f[2 * c] - bf2f(h0));
                unsigned short l1 = f2bf(f[2 * c + 1] - bf2f(h1));
                lw[c] = (unsigned int)l0 | ((unsigned int)l1 << 16);
            }
            unsigned int* dsth = (unsigned int*)&Kh[st * ATS + sd];
            unsigned int* dstl = (unsigned int*)&KlV[st * ATS + sd];
            *(uint4*)(dsth)     = make_uint4(hw[0], hw[1], hw[2], hw[3]);
            *(uint4*)(dsth + 4) = make_uint4(hw[4], hw[5], hw[6], hw[7]);
            *(uint4*)(dstl)     = make_uint4(lw[0], lw[1], lw[2], lw[3]);
            *(uint4*)(dstl + 4) = make_uint4(lw[4], lw[5], lw[6], lw[7]);
        }
        __syncthreads();

        // ---- QK^T (split-bf16, 3 passes) -> S rows wave*16.., cols 0..63
        f32x4 s[4];
        #pragma unroll
        for (int n = 0; n < 4; n++) s[n] = (f32x4)0.f;
        #pragma unroll
        for (int kc = 0; kc < 64; kc += 32) {
            bh8 qa = *(bh8*)&Qh[(wave * 16 + l15) * ATS + kc + rg * 8];
            bh8 ql = *(bh8*)&Ql[(wave * 16 + l15) * ATS + kc + rg * 8];
            #pragma unroll
            for (int n = 0; n < 4; n++) {
                bh8 ka = *(bh8*)&Kh[(n * 16 + l15) * ATS + kc + rg * 8];
                bh8 kl = *(bh8*)&KlV[(n * 16 + l15) * ATS + kc + rg * 8];
                s[n] = __builtin_amdgcn_mfma_f32_16x16x32_bf16(qa, ka, s[n], 0, 0, 0);
                s[n] = __builtin_amdgcn_mfma_f32_16x16x32_bf16(qa, kl, s[n], 0, 0, 0);
                s[n] = __builtin_amdgcn_mfma_f32_16x16x32_bf16(ql, ka, s[n], 0, 0, 0);
            }
        }

        if (kt == qt) {   // causal mask within diagonal tile
            #pragma unroll
            for (int n = 0; n < 4; n++)
                #pragma unroll
                for (int e = 0; e < 4; e++)
                    if (n * 16 + l15 > wave * 16 + rg * 4 + e) s[n][e] = -1e30f;
        }

        // ---- online softmax (C-layout rows rg*4+e; reduce over l15 lanes)
        float al[4];
        #pragma unroll
        for (int e = 0; e < 4; e++) {
            float mx = fmaxf(fmaxf(s[0][e], s[1][e]), fmaxf(s[2][e], s[3][e]));
            #pragma unroll
            for (int off = 1; off < 16; off <<= 1) mx = fmaxf(mx, __shfl_xor(mx, off));
            float mn = fmaxf(m[e], mx);
            al[e] = __expf(m[e] - mn);
            m[e] = mn;
            float rs = 0.f, rs2 = 0.f;
            #pragma unroll
            for (int n = 0; n < 4; n++) {
                float pv = __expf(s[n][e] - mn);
                s[n][e] = pv;
                rs += pv; rs2 += pv * pv;
            }
            #pragma unroll
            for (int off = 1; off < 16; off <<= 1) {
                rs  += __shfl_xor(rs, off);
                rs2 += __shfl_xor(rs2, off);
            }
            l[e]  = l[e] * al[e] + rs;
            s2[e] = s2[e] * al[e] * al[e] + rs2;
        }

        __syncthreads();   // all QK reads of KlV done
        {   // V^T tile into KlV space; P (bf16) into Ps
            unsigned short* dv = &KlV[st * ATS + sd];
            *(uint4*)(dv)     = vt0;
            *(uint4*)(dv + 8) = vt1;
            #pragma unroll
            for (int n = 0; n < 4; n++)
                #pragma unroll
                for (int e = 0; e < 4; e++)
                    Ps[(wave * 16 + rg * 4 + e) * ATS + n * 16 + l15] = f2bf(s[n][e]);
        }
        __syncthreads();   // Vs visible to all waves (Ps is intra-wave)

        // ---- rescale O, then P @ V
        #pragma unroll
        for (int n = 0; n < 4; n++)
            #pragma unroll
            for (int e = 0; e < 4; e++) o[n][e] *= al[e];

        #pragma unroll
        for (int kc = 0; kc < 64; kc += 32) {
            bh8 pa = *(bh8*)&Ps[(wave * 16 + l15) * ATS + kc + rg * 8];
            #pragma unroll
            for (int n = 0; n < 4; n++) {
                bh8 vb = *(bh8*)&KlV[(n * 16 + l15) * ATS + kc + rg * 8];
                o[n] = __builtin_amdgcn_mfma_f32_16x16x32_bf16(pa, vb, o[n], 0, 0, 0);
            }
        }
    }

    float linv[4];
    #pragma unroll
    for (int e = 0; e < 4; e++) linv[e] = 1.f / l[e];

    float en = 0.f;
    #pragma unroll
    for (int e = 0; e < 4; e++) en += s2[e] * linv[e] * linv[e];
    en += __shfl_xor(en, 16);
    en += __shfl_xor(en, 32);
    if (lane == 0) atomicAdd(&He[b * NHEAD + h], (double)en);

    #pragma unroll
    for (int n = 0; n < 4; n++)
        #pragma unroll
        for (int e = 0; e < 4; e++) {
            int row = qt * 64 + wave * 16 + rg * 4 + e;
            Ctx[((size_t)b * T_SEQ + row) * D_MODEL + h * HDIM + n * 16 + l15] =
                f2bf(o[n][e] * linv[e]);
        }
}

// ---------------------------------------------------------------------------
// Per-batch head selection (unchanged).
// ---------------------------------------------------------------------------
__global__ void headsel(const double* __restrict__ He, float* __restrict__ Mask)
{
    int b = threadIdx.x;
    if (b >= BATCH) return;
    double e[NHEAD];
    double mx = -1e300;
    for (int h = 0; h < NHEAD; h++) {
        e[h] = He[b * NHEAD + h] / (1024.0 * 1024.0);
        mx = fmax(mx, e[h]);
    }
    double p[NHEAD], s = 0.0;
    for (int h = 0; h < NHEAD; h++) { p[h] = exp(e[h] - mx); s += p[h]; }
    double ent = 0.0;
    for (int h = 0; h < NHEAD; h++) {
        double ph = p[h] / s;
        ent -= ph * log(ph + 1e-9);
    }
    double entn = ent / log(16.0);
    entn = fmin(fmax(entn, 0.0), 1.0);
    int keep = (int)rint(2.0 + entn * 4.0);
    if (keep < 1) keep = 1;
    if (keep > NHEAD) keep = NHEAD;
    double srt[NHEAD];
    for (int h = 0; h < NHEAD; h++) srt[h] = e[h];
    for (int i = 1; i < NHEAD; i++) {
        double v = srt[i]; int j = i - 1;
        while (j >= 0 && srt[j] < v) { srt[j + 1] = srt[j]; j--; }
        srt[j + 1] = v;
    }
    double th = srt[keep - 1];
    for (int h = 0; h < NHEAD; h++)
        Mask[b * NHEAD + h] = (e[h] >= th) ? 1.0f : 0.0f;
}

// ---------------------------------------------------------------------------
extern "C" void kernel_launch(void* const* d_in, const int* in_sizes, int n_in,
                              void* d_out, int out_size, void* d_ws, size_t ws_size,
                              hipStream_t stream)
{
    (void)in_sizes; (void)n_in; (void)out_size; (void)ws_size;
    const float* x  = (const float*)d_in[0];
    const float* qw = (const float*)d_in[1];
    const float* qb = (const float*)d_in[2];
    const float* kw = (const float*)d_in[3];
    const float* kb = (const float*)d_in[4];
    const float* vw = (const float*)d_in[5];
    const float* vb = (const float*)d_in[6];
    const float* ow = (const float*)d_in[7];
    const float* ob = (const float*)d_in[8];
    float* out = (float*)d_out;

    char* base = (char*)d_ws;
    const size_t MB = (size_t)1024 * 1024;
    float*          q_hm = (float*)(base);                    // 16 MB head-major
    float*          k_hm = (float*)(base + 16 * MB);          // 16 MB head-major
    unsigned short* vt   = (unsigned short*)(base + 32 * MB); // 8 MB V^T bf16
    unsigned short* ctxb = (unsigned short*)(base + 40 * MB); // 8 MB bf16
    unsigned short* kwh  = (unsigned short*)(base + 48 * MB); // 2 MB
    unsigned short* kwl  = (unsigned short*)(base + 50 * MB);
    unsigned short* vwb  = (unsigned short*)(base + 52 * MB);
    unsigned short* owb  = (unsigned short*)(base + 54 * MB);
    double*         he   = (double*)(base + 56 * MB);
    float*          mask = (float*)(base + 56 * MB + 512);
    // q-path scratch: digit planes OVERLAY vt+ctxb (32..48 MB) — dig is
    // consumed by gemm_q_i8 before v-proj/attn write vt/ctxb. sg at 57 MB.
    signed char*    dig  = (signed char*)(base + 32 * MB);    // 16 MB (4 planes)
    signed char*    sg   = (signed char*)(base + 57 * MB);    // 1 MB

    hipMemsetAsync(he, 0, 64 * sizeof(double), stream);

    cast_weights<<<1536, 256, 0, stream>>>(kw, kwh, kwl, vw, vwb, ow, owb);
    prep_q<<<2560, 256, 0, stream>>>(x, dig, qw, sg);
    // q projection: exact int8-digit MFMA (deterministic, noise ~1.1e-6)
    gemm_q_i8<<<dim3(16, 64), 256, 0, stream>>>(dig, sg, qb, q_hm);
    // k projection: split-bf16 MFMA, fp32 head-major out
    gemm_xsplit<<<dim3(8, 32), 256, 0, stream>>>(x, kwh, kwl, kb, k_hm, nullptr, 1);
    // v projection: bf16 MFMA, V^T bf16 out (writes vt AFTER dig consumed)
    gemm_xsplit<<<dim3(8, 32), 256, 0, stream>>>(x, vwb, nullptr, vb, nullptr, vt, 0);
    normqk<<<dim3(16384, 2), 256, 0, stream>>>(q_hm, k_hm);
    attn_kernel<<<dim3(16, 16, 4), 256, 0, stream>>>(q_hm, k_hm, vt, ctxb, he);
    headsel<<<1, 64, 0, stream>>>(he, mask);
    gemm_obf<<<dim3(8, 32), 256, 0, stream>>>(ctxb, owb, ob, out, mask);
}